// Round 9
// baseline (1951.494 us; speedup 1.0000x reference)
//
#include <hip/hip_runtime.h>

#define BB 32
#define TT 2048
#define CC 64
#define BT (BB * TT)
#define NCH 128
#define CL 16  // chunk length; NCH*CL == TT
#define GN_EPS (1e-5f * 64.f)

// ---- cross-lane helpers --------------------------------------------------
__device__ __forceinline__ float rl(float v, int lane) {
  return __uint_as_float(__builtin_amdgcn_readlane(__float_as_uint(v), lane));
}
template <int CTRL>
__device__ __forceinline__ float dppadd(float x) {
  return x + __int_as_float(__builtin_amdgcn_update_dpp(
                 0, __float_as_int(x), CTRL, 0xf, 0xf, true));
}
// Full wave64 sum -> broadcast.
__device__ __forceinline__ float wave_red_sum(float x) {
  x = dppadd<0x111>(x);  // row_shr:1
  x = dppadd<0x112>(x);  // row_shr:2
  x = dppadd<0x114>(x);  // row_shr:4
  x = dppadd<0x118>(x);  // row_shr:8
  x = dppadd<0x142>(x);  // row_bcast:15
  x = dppadd<0x143>(x);  // row_bcast:31
  return __uint_as_float(__builtin_amdgcn_readlane(__float_as_uint(x), 63));
}
__device__ __forceinline__ float tanh_f(float x) {
  x = fminf(fmaxf(x, -10.f), 10.f);
  const float e = __expf(2.f * x);
  return (e - 1.f) / (e + 1.f);
}

// ---- mix: token-shift + maa mixing + decay MLP; LDS phased 40KB ----------
__global__ __launch_bounds__(512, 4) void mix_kernel(
    const float* __restrict__ x,
    const float* __restrict__ tm_x, const float* __restrict__ tm_w, const float* __restrict__ tm_k,
    const float* __restrict__ tm_v, const float* __restrict__ tm_r, const float* __restrict__ tm_g,
    const float* __restrict__ maa_w1, const float* __restrict__ maa_w2,
    const float* __restrict__ t_decay, const float* __restrict__ dec_w1,
    const float* __restrict__ dec_w2,
    float* __restrict__ xk_o, float* __restrict__ xv_o,
    float* __restrict__ xr_o, float* __restrict__ xg_o,
    float* __restrict__ d_o)
{
  __shared__ float lds[10240];              // 40KB, reused across 3 phases
  float2* w1a = (float2*)lds;               // phase1: 4096 float2
  float*  w1c = lds + 8192;                 //         2048 floats
  float4* w2a = (float4*)lds;               // phase2: 2048 float4
  float*  w2b = lds + 8192;                 //         2048 floats
  float2* decW = (float2*)lds;              // phase3: 4096 float2

  const int tid = threadIdx.x;
  // ---- phase 1: w1 ----
  for (int idx = tid; idx < 4096; idx += 512) {
    const int c = idx >> 6, jj = idx & 63;
    w1a[idx] = make_float2(maa_w1[c * 160 + jj], maa_w1[c * 160 + 64 + jj]);
  }
  for (int idx = tid; idx < 2048; idx += 512) {
    const int c = idx >> 5, jj = idx & 31;
    w1c[idx] = maa_w1[c * 160 + 128 + jj];
  }
  __syncthreads();

  const int w = tid >> 6, j = tid & 63;
  const int j32 = j & 31;
  const int bt0 = blockIdx.x * 32 + w * 4;
  const float tmx = tm_x[j], tmw = tm_w[j], tmk = tm_k[j],
              tmv = tm_v[j], tmr = tm_r[j], tmg = tm_g[j];

  float xc[4], xx[4], xxx[4];
#pragma unroll
  for (int q = 0; q < 4; ++q) {
    const int bt = bt0 + q;
    const int t = bt & (TT - 1);
    const float cur = x[(size_t)bt * CC + j];
    const float prv = (t != 0) ? x[(size_t)(bt - 1) * CC + j] : 0.f;
    xc[q] = cur;
    xx[q] = prv - cur;
    xxx[q] = fmaf(xx[q], tmx, cur);
  }

  float a0[4] = {0, 0, 0, 0}, a1[4] = {0, 0, 0, 0}, a2[4] = {0, 0, 0, 0};
#pragma unroll
  for (int c = 0; c < 64; ++c) {
    const float2 wv = w1a[c * 64 + j];
    const float wc = w1c[c * 32 + j32];
#pragma unroll
    for (int q = 0; q < 4; ++q) {
      const float s = rl(xxx[q], c);
      a0[q] = fmaf(s, wv.x, a0[q]);
      a1[q] = fmaf(s, wv.y, a1[q]);
      a2[q] = fmaf(s, wc, a2[q]);
    }
  }
#pragma unroll
  for (int q = 0; q < 4; ++q) {
    a0[q] = tanh_f(a0[q]); a1[q] = tanh_f(a1[q]); a2[q] = tanh_f(a2[q]);
  }

  // ---- phase 2: w2 ----
  __syncthreads();  // done reading w1
  for (int idx = tid; idx < 2048; idx += 512) {
    const int q = idx >> 6, jj = idx & 63;
    w2a[idx] = make_float4(maa_w2[q * 64 + jj], maa_w2[(32 + q) * 64 + jj],
                           maa_w2[(64 + q) * 64 + jj], maa_w2[(96 + q) * 64 + jj]);
    w2b[idx] = maa_w2[(128 + q) * 64 + jj];
  }
  __syncthreads();

  float m0[4] = {0,0,0,0}, m1[4] = {0,0,0,0}, m2[4] = {0,0,0,0},
        m3[4] = {0,0,0,0}, m4[4] = {0,0,0,0};
#pragma unroll
  for (int q2 = 0; q2 < 32; ++q2) {
    const float4 w4 = w2a[q2 * 64 + j];
    const float w5 = w2b[q2 * 64 + j];
#pragma unroll
    for (int q = 0; q < 4; ++q) {
      m0[q] = fmaf(rl(a0[q], q2),      w4.x, m0[q]);
      m1[q] = fmaf(rl(a0[q], 32 + q2), w4.y, m1[q]);
      m2[q] = fmaf(rl(a1[q], q2),      w4.z, m2[q]);
      m3[q] = fmaf(rl(a1[q], 32 + q2), w4.w, m3[q]);
      m4[q] = fmaf(rl(a2[q], q2),      w5,   m4[q]);
    }
  }
  float xw[4];
#pragma unroll
  for (int q = 0; q < 4; ++q) {
    const size_t o = (size_t)(bt0 + q) * CC + j;
    xw[q] = fmaf(xx[q], tmw + m0[q], xc[q]);   // kept in registers
    xk_o[o] = fmaf(xx[q], tmk + m1[q], xc[q]);
    xv_o[o] = fmaf(xx[q], tmv + m2[q], xc[q]);
    xr_o[o] = fmaf(xx[q], tmr + m3[q], xc[q]);
    xg_o[o] = fmaf(xx[q], tmg + m4[q], xc[q]);
  }

  // ---- phase 3: decay MLP ----
  __syncthreads();  // done reading w2
  for (int idx = tid; idx < 4096; idx += 512)
    decW[idx] = make_float2(dec_w1[idx], dec_w2[idx]);
  __syncthreads();

  const float td = t_decay[j];
  float hh[4] = {0,0,0,0};
#pragma unroll
  for (int c = 0; c < 64; ++c) {
    const float dw = decW[c * 64 + j].x;
#pragma unroll
    for (int q = 0; q < 4; ++q) hh[q] = fmaf(rl(xw[q], c), dw, hh[q]);
  }
#pragma unroll
  for (int q = 0; q < 4; ++q) hh[q] = tanh_f(hh[q]);

  float wf[4] = {td, td, td, td};
#pragma unroll
  for (int c = 0; c < 64; ++c) {
    const float dw = decW[c * 64 + j].y;
#pragma unroll
    for (int q = 0; q < 4; ++q) wf[q] = fmaf(rl(hh[q], c), dw, wf[q]);
  }
#pragma unroll
  for (int q = 0; q < 4; ++q)
    d_o[(size_t)(bt0 + q) * CC + j] = __expf(-__expf(wf[q]));  // coalesced
}

// ---- proj4: r,k,v,g projections + ct; single-phase 64KB, clean writes ----
__global__ __launch_bounds__(512, 4) void proj4_kernel(
    const float* __restrict__ xk_i, const float* __restrict__ xv_i,
    const float* __restrict__ xr_i, const float* __restrict__ xg_i,
    const float* __restrict__ u,
    const float* __restrict__ Wr, const float* __restrict__ Wk, const float* __restrict__ Wv,
    const float* __restrict__ Wg,
    float* __restrict__ r_o, float* __restrict__ k_o, float* __restrict__ ct_o,
    float* __restrict__ v_o, float* __restrict__ g_o)
{
  __shared__ float4 projW[4096];   // {Wr^T, Wk^T, Wv^T, Wg^T}[c][j]  64KB
  const int tid = threadIdx.x;
  for (int idx = tid; idx < 4096; idx += 512) {
    const int c = idx >> 6, jj = idx & 63;
    projW[idx] = make_float4(Wr[jj * 64 + c], Wk[jj * 64 + c],
                             Wv[jj * 64 + c], Wg[jj * 64 + c]);
  }
  __syncthreads();

  const int w = tid >> 6, j = tid & 63;
  const int bt0 = blockIdx.x * 32 + w * 4;
  const float u_j = u[j];

  float xk[4], xv_[4], xr[4], xg[4];
#pragma unroll
  for (int q = 0; q < 4; ++q) {
    const size_t o = (size_t)(bt0 + q) * CC + j;
    xk[q] = xk_i[o]; xv_[q] = xv_i[o]; xr[q] = xr_i[o]; xg[q] = xg_i[o];
  }

  float ar[4] = {0,0,0,0}, ak[4] = {0,0,0,0}, av[4] = {0,0,0,0}, ag[4] = {0,0,0,0};
#pragma unroll
  for (int c = 0; c < 64; ++c) {
    const float4 wv = projW[c * 64 + j];
#pragma unroll
    for (int q = 0; q < 4; ++q) {
      ar[q] = fmaf(rl(xr[q], c),  wv.x, ar[q]);
      ak[q] = fmaf(rl(xk[q], c),  wv.y, ak[q]);
      av[q] = fmaf(rl(xv_[q], c), wv.z, av[q]);
      ag[q] = fmaf(rl(xg[q], c),  wv.w, ag[q]);
    }
  }

#pragma unroll
  for (int q = 0; q < 4; ++q) {
    const size_t o = (size_t)(bt0 + q) * CC + j;
    const float ct = wave_red_sum(ar[q] * u_j * ak[q]);  // sum_i r_i u_i k_i
    r_o[o] = ar[q];                       // all coalesced full-line writes
    k_o[o] = ak[q];
    v_o[o] = av[q];
    g_o[o] = ag[q] / (1.f + __expf(-ag[q]));  // silu
    if (j == 0) ct_o[bt0 + q] = ct;
  }
}

// ---- A: chunk-local state. Wave = (b,ch); lane = j; S[i] in 64 VGPRs. ----
// k/d rows are wave-uniform -> scalar loads; v_j / d_j per-lane coalesced.
__global__ __launch_bounds__(256, 4) void chunkA_kernel(
    const float* __restrict__ kb, const float* __restrict__ db,
    const float* __restrict__ v_i,
    float* __restrict__ Sloc, float* __restrict__ Dp)
{
  const int lane = threadIdx.x & 63;
  const int bch = __builtin_amdgcn_readfirstlane((blockIdx.x << 2) + (threadIdx.x >> 6));
  const float* kq = kb + (size_t)bch * (CL * CC);
  const float* dq = db + (size_t)bch * (CL * CC);
  const float* vq = v_i + (size_t)bch * (CL * CC) + lane;

  float S[CC];
#pragma unroll
  for (int i = 0; i < CC; ++i) S[i] = 0.f;
  float dp = 1.f;

  for (int t = 0; t < CL; ++t) {
    const float* kt = kq + t * CC;
    const float* dt = dq + t * CC;
    const float vv = vq[t * CC];
    dp *= dt[lane];
#pragma unroll
    for (int i = 0; i < CC; ++i) {
      S[i] = fmaf(dt[i], S[i], kt[i] * vv);  // kt[i], dt[i] uniform -> s_load
    }
  }
  float* so = Sloc + (size_t)bch * (CC * CC) + lane;
#pragma unroll
  for (int i = 0; i < CC; ++i) so[i * CC] = S[i];
  Dp[(size_t)bch * CC + lane] = dp;
}

// ---- B: parallel combine: one thread per (b, i, j) element ---------------
__global__ __launch_bounds__(256) void combine_kernel(
    float* __restrict__ buf, const float* __restrict__ Dp)
{
  const int g = blockIdx.x * 256 + threadIdx.x;  // BB*4096 threads
  const int b = g >> 12;
  const int idx = g & 4095;
  const int i = idx >> 6;
  float run = 0.f;
  for (int ch = 0; ch < NCH; ++ch) {
    const size_t base = ((size_t)(b * NCH + ch)) * (CC * CC);
    const float tmp = buf[base + idx];
    buf[base + idx] = run;
    run = fmaf(run, Dp[((size_t)b * NCH + ch) * CC + i], tmp);
  }
}

// ---- C: emit + GroupNorm + *g + @Wo.T fused ------------------------------
__global__ __launch_bounds__(256, 4) void scanC_kernel(
    const float* __restrict__ rb, const float* __restrict__ kb,
    const float* __restrict__ db, const float* __restrict__ ctb,
    const float* __restrict__ v_i,
    const float* __restrict__ S0, const float* __restrict__ g_i,
    const float* __restrict__ ln_w, const float* __restrict__ ln_b,
    const float* __restrict__ Wo, float* __restrict__ out)
{
  __shared__ float WoT[4096];  // Wo^T[c][j] 16KB
  for (int idx = threadIdx.x; idx < 4096; idx += 256) {
    const int c = idx >> 6, jj = idx & 63;
    WoT[idx] = Wo[jj * 64 + c];
  }
  __syncthreads();

  const int lane = threadIdx.x & 63;
  const int bch = __builtin_amdgcn_readfirstlane((blockIdx.x << 2) + (threadIdx.x >> 6));
  const float* rq = rb + (size_t)bch * (CL * CC);
  const float* kq = kb + (size_t)bch * (CL * CC);
  const float* dq = db + (size_t)bch * (CL * CC);
  const float* cq = ctb + (size_t)bch * CL;
  const float* vq = v_i + (size_t)bch * (CL * CC) + lane;
  const float* gq = g_i + (size_t)bch * (CL * CC) + lane;
  float* oq = out + (size_t)bch * (CL * CC) + lane;
  const float lnw = ln_w[lane], lnb = ln_b[lane];

  float S[CC];
  const float* si = S0 + (size_t)bch * (CC * CC) + lane;
#pragma unroll
  for (int i = 0; i < CC; ++i) S[i] = si[i * CC];

  for (int t = 0; t < CL; ++t) {
    const float* rt = rq + t * CC;
    const float* kt = kq + t * CC;
    const float* dt = dq + t * CC;
    const float vv = vq[t * CC];
    float y0 = cq[t] * vv, y1 = 0.f;   // ct*v_j + sum_i r_i*S_old
#pragma unroll
    for (int i = 0; i < CC; i += 2) {
      y0 = fmaf(rt[i], S[i], y0);
      S[i] = fmaf(dt[i], S[i], kt[i] * vv);
      y1 = fmaf(rt[i + 1], S[i + 1], y1);
      S[i + 1] = fmaf(dt[i + 1], S[i + 1], kt[i + 1] * vv);
    }
    const float y = y0 + y1;  // y[t][lane]

    // GroupNorm(64) across lanes + silu(g) + Wo matvec
    const float s1 = wave_red_sum(y);
    const float s2 = wave_red_sum(y * y);
    const float mu = s1 * (1.f / CC);
    const float var = s2 * (1.f / CC) - mu * mu;
    const float z = (y - mu) * rsqrtf(var + GN_EPS) * lnw + lnb;
    const float sz = z * gq[t * CC];
    float acc = 0.f;
#pragma unroll
    for (int c = 0; c < CC; ++c) acc = fmaf(rl(sz, c), WoT[c * 64 + lane], acc);
    oq[t * CC] = acc;
  }
}

extern "C" void kernel_launch(void* const* d_in, const int* in_sizes, int n_in,
                              void* d_out, int out_size, void* d_ws, size_t ws_size,
                              hipStream_t stream) {
  const float* x       = (const float*)d_in[0];
  const float* tm_x    = (const float*)d_in[1];
  const float* tm_w    = (const float*)d_in[2];
  const float* tm_k    = (const float*)d_in[3];
  const float* tm_v    = (const float*)d_in[4];
  const float* tm_r    = (const float*)d_in[5];
  const float* tm_g    = (const float*)d_in[6];
  const float* maa_w1  = (const float*)d_in[7];
  const float* maa_w2  = (const float*)d_in[8];
  const float* t_decay = (const float*)d_in[9];
  const float* dec_w1  = (const float*)d_in[10];
  const float* dec_w2  = (const float*)d_in[11];
  const float* u       = (const float*)d_in[12];
  const float* Wr      = (const float*)d_in[13];
  const float* Wk      = (const float*)d_in[14];
  const float* Wv      = (const float*)d_in[15];
  const float* Wg      = (const float*)d_in[16];
  const float* Wo      = (const float*)d_in[17];
  const float* ln_w    = (const float*)d_in[18];
  const float* ln_b    = (const float*)d_in[19];

  const size_t M = (size_t)BT * CC;  // 4.19M floats
  float* ws   = (float*)d_ws;
  float* xk_o = ws;                  // [0,M)   dead after proj4
  float* xv_o = ws + M;              // [M,2M)
  float* xr_o = ws + 2 * M;          // [2M,3M)
  float* xg_o = ws + 3 * M;          // [3M,4M)
  float* g_o  = ws + 4 * M;          // alive until scanC
  float* v_o  = ws + 5 * M;          // alive until scanC
  float* r_o  = ws + 6 * M;          // separate streams (clean writes)
  float* k_o  = ws + 7 * M;
  float* d_o  = ws + 8 * M;
  float* ct_o = ws + 9 * M;          // BT floats
  float* scb  = ws;                  // Sloc/S0 in place: BB*NCH*4096 = [0,4M)
  float* out  = (float*)d_out;
  float* Dp   = out;                 // BB*NCH*CC scratch; scanC overwrites out

  mix_kernel<<<2048, 512, 0, stream>>>(
      x, tm_x, tm_w, tm_k, tm_v, tm_r, tm_g, maa_w1, maa_w2,
      t_decay, dec_w1, dec_w2,
      xk_o, xv_o, xr_o, xg_o, d_o);

  proj4_kernel<<<2048, 512, 0, stream>>>(
      xk_o, xv_o, xr_o, xg_o, u, Wr, Wk, Wv, Wg, r_o, k_o, ct_o, v_o, g_o);

  chunkA_kernel<<<(BB * NCH) / 4, 256, 0, stream>>>(
      k_o, d_o, v_o, scb, Dp);

  combine_kernel<<<(BB * 4096) / 256, 256, 0, stream>>>(scb, Dp);

  scanC_kernel<<<(BB * NCH) / 4, 256, 0, stream>>>(
      r_o, k_o, d_o, ct_o, v_o, scb, g_o, ln_w, ln_b, Wo, out);
}

// Round 10
// 1889.115 us; speedup vs baseline: 1.0330x; 1.0330x over previous
//
#include <hip/hip_runtime.h>

#define BB 32
#define TT 2048
#define CC 64
#define BT (BB * TT)
#define NCH 64
#define CL 32  // chunk length; NCH*CL == TT
#define GN_EPS (1e-5f * 64.f)

// ---- cross-lane helpers --------------------------------------------------
__device__ __forceinline__ float rl(float v, int lane) {
  return __uint_as_float(__builtin_amdgcn_readlane(__float_as_uint(v), lane));
}
template <int CTRL>
__device__ __forceinline__ float dppadd(float x) {
  return x + __int_as_float(__builtin_amdgcn_update_dpp(
                 0, __float_as_int(x), CTRL, 0xf, 0xf, true));
}
// Full wave64 sum -> broadcast.
__device__ __forceinline__ float wave_red_sum(float x) {
  x = dppadd<0x111>(x);  // row_shr:1
  x = dppadd<0x112>(x);  // row_shr:2
  x = dppadd<0x114>(x);  // row_shr:4
  x = dppadd<0x118>(x);  // row_shr:8
  x = dppadd<0x142>(x);  // row_bcast:15
  x = dppadd<0x143>(x);  // row_bcast:31
  return __uint_as_float(__builtin_amdgcn_readlane(__float_as_uint(x), 63));
}
__device__ __forceinline__ float tanh_f(float x) {
  x = fminf(fmaxf(x, -10.f), 10.f);
  const float e = __expf(2.f * x);
  return (e - 1.f) / (e + 1.f);
}

// ---- mix: token-shift + maa mixing + decay MLP; LDS phased 40KB ----------
// All global weight reads here are contiguous (no transpose staging needed).
__global__ __launch_bounds__(512, 4) void mix_kernel(
    const float* __restrict__ x,
    const float* __restrict__ tm_x, const float* __restrict__ tm_w, const float* __restrict__ tm_k,
    const float* __restrict__ tm_v, const float* __restrict__ tm_r, const float* __restrict__ tm_g,
    const float* __restrict__ maa_w1, const float* __restrict__ maa_w2,
    const float* __restrict__ t_decay, const float* __restrict__ dec_w1,
    const float* __restrict__ dec_w2,
    float* __restrict__ xk_o, float* __restrict__ xv_o,
    float* __restrict__ xr_o, float* __restrict__ xg_o,
    float* __restrict__ d_o)
{
  __shared__ float lds[10240];              // 40KB, reused across 3 phases
  float2* w1a = (float2*)lds;               // phase1: 4096 float2
  float*  w1c = lds + 8192;                 //         2048 floats
  float4* w2a = (float4*)lds;               // phase2: 2048 float4
  float*  w2b = lds + 8192;                 //         2048 floats
  float2* decW = (float2*)lds;              // phase3: 4096 float2

  const int tid = threadIdx.x;
  // ---- phase 1: w1 ----
  for (int idx = tid; idx < 4096; idx += 512) {
    const int c = idx >> 6, jj = idx & 63;
    w1a[idx] = make_float2(maa_w1[c * 160 + jj], maa_w1[c * 160 + 64 + jj]);
  }
  for (int idx = tid; idx < 2048; idx += 512) {
    const int c = idx >> 5, jj = idx & 31;
    w1c[idx] = maa_w1[c * 160 + 128 + jj];
  }
  __syncthreads();

  const int w = tid >> 6, j = tid & 63;
  const int j32 = j & 31;
  const int bt0 = blockIdx.x * 32 + w * 4;
  const float tmx = tm_x[j], tmw = tm_w[j], tmk = tm_k[j],
              tmv = tm_v[j], tmr = tm_r[j], tmg = tm_g[j];

  float xc[4], xx[4], xxx[4];
#pragma unroll
  for (int q = 0; q < 4; ++q) {
    const int bt = bt0 + q;
    const int t = bt & (TT - 1);
    const float cur = x[(size_t)bt * CC + j];
    const float prv = (t != 0) ? x[(size_t)(bt - 1) * CC + j] : 0.f;
    xc[q] = cur;
    xx[q] = prv - cur;
    xxx[q] = fmaf(xx[q], tmx, cur);
  }

  float a0[4] = {0, 0, 0, 0}, a1[4] = {0, 0, 0, 0}, a2[4] = {0, 0, 0, 0};
#pragma unroll
  for (int c = 0; c < 64; ++c) {
    const float2 wv = w1a[c * 64 + j];
    const float wc = w1c[c * 32 + j32];
#pragma unroll
    for (int q = 0; q < 4; ++q) {
      const float s = rl(xxx[q], c);
      a0[q] = fmaf(s, wv.x, a0[q]);
      a1[q] = fmaf(s, wv.y, a1[q]);
      a2[q] = fmaf(s, wc, a2[q]);
    }
  }
#pragma unroll
  for (int q = 0; q < 4; ++q) {
    a0[q] = tanh_f(a0[q]); a1[q] = tanh_f(a1[q]); a2[q] = tanh_f(a2[q]);
  }

  // ---- phase 2: w2 ----
  __syncthreads();  // done reading w1
  for (int idx = tid; idx < 2048; idx += 512) {
    const int q = idx >> 6, jj = idx & 63;
    w2a[idx] = make_float4(maa_w2[q * 64 + jj], maa_w2[(32 + q) * 64 + jj],
                           maa_w2[(64 + q) * 64 + jj], maa_w2[(96 + q) * 64 + jj]);
    w2b[idx] = maa_w2[(128 + q) * 64 + jj];
  }
  __syncthreads();

  float m0[4] = {0,0,0,0}, m1[4] = {0,0,0,0}, m2[4] = {0,0,0,0},
        m3[4] = {0,0,0,0}, m4[4] = {0,0,0,0};
#pragma unroll
  for (int q2 = 0; q2 < 32; ++q2) {
    const float4 w4 = w2a[q2 * 64 + j];
    const float w5 = w2b[q2 * 64 + j];
#pragma unroll
    for (int q = 0; q < 4; ++q) {
      m0[q] = fmaf(rl(a0[q], q2),      w4.x, m0[q]);
      m1[q] = fmaf(rl(a0[q], 32 + q2), w4.y, m1[q]);
      m2[q] = fmaf(rl(a1[q], q2),      w4.z, m2[q]);
      m3[q] = fmaf(rl(a1[q], 32 + q2), w4.w, m3[q]);
      m4[q] = fmaf(rl(a2[q], q2),      w5,   m4[q]);
    }
  }
  float xw[4];
#pragma unroll
  for (int q = 0; q < 4; ++q) {
    const size_t o = (size_t)(bt0 + q) * CC + j;
    xw[q] = fmaf(xx[q], tmw + m0[q], xc[q]);   // kept in registers
    xk_o[o] = fmaf(xx[q], tmk + m1[q], xc[q]);
    xv_o[o] = fmaf(xx[q], tmv + m2[q], xc[q]);
    xr_o[o] = fmaf(xx[q], tmr + m3[q], xc[q]);
    xg_o[o] = fmaf(xx[q], tmg + m4[q], xc[q]);
  }

  // ---- phase 3: decay MLP ----
  __syncthreads();  // done reading w2
  for (int idx = tid; idx < 4096; idx += 512)
    decW[idx] = make_float2(dec_w1[idx], dec_w2[idx]);
  __syncthreads();

  const float td = t_decay[j];
  float hh[4] = {0,0,0,0};
#pragma unroll
  for (int c = 0; c < 64; ++c) {
    const float dw = decW[c * 64 + j].x;
#pragma unroll
    for (int q = 0; q < 4; ++q) hh[q] = fmaf(rl(xw[q], c), dw, hh[q]);
  }
#pragma unroll
  for (int q = 0; q < 4; ++q) hh[q] = tanh_f(hh[q]);

  float wf[4] = {td, td, td, td};
#pragma unroll
  for (int c = 0; c < 64; ++c) {
    const float dw = decW[c * 64 + j].y;
#pragma unroll
    for (int q = 0; q < 4; ++q) wf[q] = fmaf(rl(hh[q], c), dw, wf[q]);
  }
#pragma unroll
  for (int q = 0; q < 4; ++q)
    d_o[(size_t)(bt0 + q) * CC + j] = __expf(-__expf(wf[q]));  // coalesced
}

// ---- proj4: r,k,v,g projections + ct -------------------------------------
// Weight staging: COALESCED global read + transposed LDS write (pad 65).
#define PJ_STRIDE 65
__global__ __launch_bounds__(512, 4) void proj4_kernel(
    const float* __restrict__ xk_i, const float* __restrict__ xv_i,
    const float* __restrict__ xr_i, const float* __restrict__ xg_i,
    const float* __restrict__ u,
    const float* __restrict__ Wr, const float* __restrict__ Wk, const float* __restrict__ Wv,
    const float* __restrict__ Wg,
    float* __restrict__ r_o, float* __restrict__ k_o, float* __restrict__ ct_o,
    float* __restrict__ v_o, float* __restrict__ g_o)
{
  __shared__ float4 projW[64 * PJ_STRIDE];  // projW[c*65+j] = {W*[j][c]}, ~66.6KB
  const int tid = threadIdx.x;
  for (int idx = tid; idx < 4096; idx += 512) {
    const int row = idx >> 6, col = idx & 63;          // row=j, col=c
    projW[col * PJ_STRIDE + row] =                     // contiguous global reads
        make_float4(Wr[idx], Wk[idx], Wv[idx], Wg[idx]);
  }
  __syncthreads();

  const int w = tid >> 6, j = tid & 63;
  const int bt0 = blockIdx.x * 32 + w * 4;
  const float u_j = u[j];

  float xk[4], xv_[4], xr[4], xg[4];
#pragma unroll
  for (int q = 0; q < 4; ++q) {
    const size_t o = (size_t)(bt0 + q) * CC + j;
    xk[q] = xk_i[o]; xv_[q] = xv_i[o]; xr[q] = xr_i[o]; xg[q] = xg_i[o];
  }

  float ar[4] = {0,0,0,0}, ak[4] = {0,0,0,0}, av[4] = {0,0,0,0}, ag[4] = {0,0,0,0};
#pragma unroll
  for (int c = 0; c < 64; ++c) {
    const float4 wv = projW[c * PJ_STRIDE + j];  // contiguous across lanes
#pragma unroll
    for (int q = 0; q < 4; ++q) {
      ar[q] = fmaf(rl(xr[q], c),  wv.x, ar[q]);
      ak[q] = fmaf(rl(xk[q], c),  wv.y, ak[q]);
      av[q] = fmaf(rl(xv_[q], c), wv.z, av[q]);
      ag[q] = fmaf(rl(xg[q], c),  wv.w, ag[q]);
    }
  }

#pragma unroll
  for (int q = 0; q < 4; ++q) {
    const size_t o = (size_t)(bt0 + q) * CC + j;
    const float ct = wave_red_sum(ar[q] * u_j * ak[q]);  // sum_i r_i u_i k_i
    r_o[o] = ar[q];                       // coalesced full-line writes
    k_o[o] = ak[q];
    v_o[o] = av[q];
    g_o[o] = ag[q] / (1.f + __expf(-ag[q]));  // silu
    if (j == 0) ct_o[bt0 + q] = ct;
  }
}

// ---- A: chunk-local state. Wave = (b,ch); lane = j; S[i] in 64 VGPRs. ----
__global__ __launch_bounds__(256, 4) void chunkA_kernel(
    const float* __restrict__ kb, const float* __restrict__ db,
    const float* __restrict__ v_i,
    float* __restrict__ Sloc, float* __restrict__ Dp)
{
  const int lane = threadIdx.x & 63;
  const int bch = __builtin_amdgcn_readfirstlane((blockIdx.x << 2) + (threadIdx.x >> 6));
  const float* kq = kb + (size_t)bch * (CL * CC);
  const float* dq = db + (size_t)bch * (CL * CC);
  const float* vq = v_i + (size_t)bch * (CL * CC) + lane;

  float S[CC];
#pragma unroll
  for (int i = 0; i < CC; ++i) S[i] = 0.f;
  float dp = 1.f;

  for (int t = 0; t < CL; ++t) {
    const float* kt = kq + t * CC;
    const float* dt = dq + t * CC;
    const float vv = vq[t * CC];
    dp *= dt[lane];
#pragma unroll
    for (int i = 0; i < CC; ++i) {
      S[i] = fmaf(dt[i], S[i], kt[i] * vv);  // kt[i], dt[i] uniform -> s_load
    }
  }
  float* so = Sloc + (size_t)bch * (CC * CC) + lane;
#pragma unroll
  for (int i = 0; i < CC; ++i) so[i * CC] = S[i];
  Dp[(size_t)bch * CC + lane] = dp;
}

// ---- B: parallel combine: one thread per (b, i, j) element ---------------
__global__ __launch_bounds__(256) void combine_kernel(
    float* __restrict__ buf, const float* __restrict__ Dp)
{
  const int g = blockIdx.x * 256 + threadIdx.x;  // BB*4096 threads
  const int b = g >> 12;
  const int idx = g & 4095;
  const int i = idx >> 6;
  float run = 0.f;
  for (int ch = 0; ch < NCH; ++ch) {
    const size_t base = ((size_t)(b * NCH + ch)) * (CC * CC);
    const float tmp = buf[base + idx];
    buf[base + idx] = run;
    run = fmaf(run, Dp[((size_t)b * NCH + ch) * CC + i], tmp);
  }
}

// ---- C: emit + GroupNorm + *g + @Wo.T fused ------------------------------
__global__ __launch_bounds__(256, 4) void scanC_kernel(
    const float* __restrict__ rb, const float* __restrict__ kb,
    const float* __restrict__ db, const float* __restrict__ ctb,
    const float* __restrict__ v_i,
    const float* __restrict__ S0, const float* __restrict__ g_i,
    const float* __restrict__ ln_w, const float* __restrict__ ln_b,
    const float* __restrict__ Wo, float* __restrict__ out)
{
  __shared__ float WoT[64 * PJ_STRIDE];  // WoT[c*65+j] = Wo[j][c], pad 65
  for (int idx = threadIdx.x; idx < 4096; idx += 256) {
    const int row = idx >> 6, col = idx & 63;          // row=j, col=c
    WoT[col * PJ_STRIDE + row] = Wo[idx];              // contiguous global reads
  }
  __syncthreads();

  const int lane = threadIdx.x & 63;
  const int bch = __builtin_amdgcn_readfirstlane((blockIdx.x << 2) + (threadIdx.x >> 6));
  const float* rq = rb + (size_t)bch * (CL * CC);
  const float* kq = kb + (size_t)bch * (CL * CC);
  const float* dq = db + (size_t)bch * (CL * CC);
  const float* cq = ctb + (size_t)bch * CL;
  const float* vq = v_i + (size_t)bch * (CL * CC) + lane;
  const float* gq = g_i + (size_t)bch * (CL * CC) + lane;
  float* oq = out + (size_t)bch * (CL * CC) + lane;
  const float lnw = ln_w[lane], lnb = ln_b[lane];

  float S[CC];
  const float* si = S0 + (size_t)bch * (CC * CC) + lane;
#pragma unroll
  for (int i = 0; i < CC; ++i) S[i] = si[i * CC];

  for (int t = 0; t < CL; ++t) {
    const float* rt = rq + t * CC;
    const float* kt = kq + t * CC;
    const float* dt = dq + t * CC;
    const float vv = vq[t * CC];
    float y0 = cq[t] * vv, y1 = 0.f;   // ct*v_j + sum_i r_i*S_old
#pragma unroll
    for (int i = 0; i < CC; i += 2) {
      y0 = fmaf(rt[i], S[i], y0);
      S[i] = fmaf(dt[i], S[i], kt[i] * vv);
      y1 = fmaf(rt[i + 1], S[i + 1], y1);
      S[i + 1] = fmaf(dt[i + 1], S[i + 1], kt[i + 1] * vv);
    }
    const float y = y0 + y1;  // y[t][lane]

    // GroupNorm(64) across lanes + silu(g) + Wo matvec
    const float s1 = wave_red_sum(y);
    const float s2 = wave_red_sum(y * y);
    const float mu = s1 * (1.f / CC);
    const float var = s2 * (1.f / CC) - mu * mu;
    const float z = (y - mu) * rsqrtf(var + GN_EPS) * lnw + lnb;
    const float sz = z * gq[t * CC];
    float acc = 0.f;
#pragma unroll
    for (int c = 0; c < CC; ++c)
      acc = fmaf(rl(sz, c), WoT[c * PJ_STRIDE + lane], acc);
    oq[t * CC] = acc;
  }
}

extern "C" void kernel_launch(void* const* d_in, const int* in_sizes, int n_in,
                              void* d_out, int out_size, void* d_ws, size_t ws_size,
                              hipStream_t stream) {
  const float* x       = (const float*)d_in[0];
  const float* tm_x    = (const float*)d_in[1];
  const float* tm_w    = (const float*)d_in[2];
  const float* tm_k    = (const float*)d_in[3];
  const float* tm_v    = (const float*)d_in[4];
  const float* tm_r    = (const float*)d_in[5];
  const float* tm_g    = (const float*)d_in[6];
  const float* maa_w1  = (const float*)d_in[7];
  const float* maa_w2  = (const float*)d_in[8];
  const float* t_decay = (const float*)d_in[9];
  const float* dec_w1  = (const float*)d_in[10];
  const float* dec_w2  = (const float*)d_in[11];
  const float* u       = (const float*)d_in[12];
  const float* Wr      = (const float*)d_in[13];
  const float* Wk      = (const float*)d_in[14];
  const float* Wv      = (const float*)d_in[15];
  const float* Wg      = (const float*)d_in[16];
  const float* Wo      = (const float*)d_in[17];
  const float* ln_w    = (const float*)d_in[18];
  const float* ln_b    = (const float*)d_in[19];

  const size_t M = (size_t)BT * CC;  // 4.19M floats
  float* ws   = (float*)d_ws;
  float* xk_o = ws;                  // [0,M)   dead after proj4
  float* xv_o = ws + M;              // [M,2M)  dead after proj4
  float* xr_o = ws + 2 * M;          // [2M,3M) dead after proj4
  float* xg_o = ws + 3 * M;          // [3M,4M) dead after proj4
  float* g_o  = ws + 4 * M;          // alive until scanC
  float* v_o  = ws + 5 * M;          // alive until scanC
  float* r_o  = ws + 6 * M;          // separate streams (clean writes)
  float* k_o  = ws + 7 * M;
  float* d_o  = ws + 8 * M;
  float* ct_o = ws + 9 * M;          // BT floats
  float* Dp   = ws + 9 * M + BT;     // BB*NCH*CC = 131072 floats
  float* scb  = ws;                  // Sloc/S0 in place: BB*NCH*4096 = 2M floats [0,2M)
  float* out  = (float*)d_out;

  mix_kernel<<<2048, 512, 0, stream>>>(
      x, tm_x, tm_w, tm_k, tm_v, tm_r, tm_g, maa_w1, maa_w2,
      t_decay, dec_w1, dec_w2,
      xk_o, xv_o, xr_o, xg_o, d_o);

  proj4_kernel<<<2048, 512, 0, stream>>>(
      xk_o, xv_o, xr_o, xg_o, u, Wr, Wk, Wv, Wg, r_o, k_o, ct_o, v_o, g_o);

  chunkA_kernel<<<(BB * NCH) / 4, 256, 0, stream>>>(
      k_o, d_o, v_o, scb, Dp);

  combine_kernel<<<(BB * 4096) / 256, 256, 0, stream>>>(scb, Dp);

  scanC_kernel<<<(BB * NCH) / 4, 256, 0, stream>>>(
      r_o, k_o, d_o, ct_o, v_o, scb, g_o, ln_w, ln_b, Wo, out);
}

// Round 11
// 447.040 us; speedup vs baseline: 4.3654x; 4.2258x over previous
//
#include <hip/hip_runtime.h>

#define BB 32
#define TT 2048
#define CC 64
#define BT (BB * TT)
#define NCH 64
#define CL 32  // chunk length; NCH*CL == TT
#define GN_EPS (1e-5f * 64.f)

// ---- cross-lane helpers --------------------------------------------------
__device__ __forceinline__ float rl(float v, int lane) {
  return __uint_as_float(__builtin_amdgcn_readlane(__float_as_uint(v), lane));
}
template <int CTRL>
__device__ __forceinline__ float dppadd(float x) {
  return x + __int_as_float(__builtin_amdgcn_update_dpp(
                 0, __float_as_int(x), CTRL, 0xf, 0xf, true));
}
// Full wave64 sum -> broadcast.
__device__ __forceinline__ float wave_red_sum(float x) {
  x = dppadd<0x111>(x);  // row_shr:1
  x = dppadd<0x112>(x);  // row_shr:2
  x = dppadd<0x114>(x);  // row_shr:4
  x = dppadd<0x118>(x);  // row_shr:8
  x = dppadd<0x142>(x);  // row_bcast:15
  x = dppadd<0x143>(x);  // row_bcast:31
  return __uint_as_float(__builtin_amdgcn_readlane(__float_as_uint(x), 63));
}
__device__ __forceinline__ float tanh_f(float x) {
  x = fminf(fmaxf(x, -10.f), 10.f);
  const float e = __expf(2.f * x);
  return (e - 1.f) / (e + 1.f);
}

// ---- mix: token-shift + maa mixing + decay MLP; LDS phased 40KB ----------
// ONLY change vs round 7: one reused 40KB LDS buffer (w1 -> w2 -> decW)
// instead of the 80KB monolith, to lift occupancy 8 -> ~24 waves/CU.
__global__ __launch_bounds__(512, 4) void mix_kernel(
    const float* __restrict__ x,
    const float* __restrict__ tm_x, const float* __restrict__ tm_w, const float* __restrict__ tm_k,
    const float* __restrict__ tm_v, const float* __restrict__ tm_r, const float* __restrict__ tm_g,
    const float* __restrict__ maa_w1, const float* __restrict__ maa_w2,
    const float* __restrict__ t_decay, const float* __restrict__ dec_w1,
    const float* __restrict__ dec_w2,
    float* __restrict__ xk_o, float* __restrict__ xv_o,
    float* __restrict__ xr_o, float* __restrict__ xg_o,
    float* __restrict__ rkdc)
{
  __shared__ float lds[10240];              // 40KB, reused across 3 phases
  float2* w1a = (float2*)lds;               // phase1: 4096 float2
  float*  w1c = lds + 8192;                 //         2048 floats
  float4* w2a = (float4*)lds;               // phase2: 2048 float4
  float*  w2b = lds + 8192;                 //         2048 floats
  float2* decW = (float2*)lds;              // phase3: 4096 float2

  const int tid = threadIdx.x;
  // ---- phase 1: w1 ----
  for (int idx = tid; idx < 4096; idx += 512) {
    const int c = idx >> 6, jj = idx & 63;
    w1a[idx] = make_float2(maa_w1[c * 160 + jj], maa_w1[c * 160 + 64 + jj]);
  }
  for (int idx = tid; idx < 2048; idx += 512) {
    const int c = idx >> 5, jj = idx & 31;
    w1c[idx] = maa_w1[c * 160 + 128 + jj];
  }
  __syncthreads();

  const int w = tid >> 6, j = tid & 63;
  const int j32 = j & 31;
  const int bt0 = blockIdx.x * 32 + w * 4;
  const float tmx = tm_x[j], tmw = tm_w[j], tmk = tm_k[j],
              tmv = tm_v[j], tmr = tm_r[j], tmg = tm_g[j];

  float xc[4], xx[4], xxx[4];
#pragma unroll
  for (int q = 0; q < 4; ++q) {
    const int bt = bt0 + q;
    const int t = bt & (TT - 1);
    const float cur = x[(size_t)bt * CC + j];
    const float prv = (t != 0) ? x[(size_t)(bt - 1) * CC + j] : 0.f;
    xc[q] = cur;
    xx[q] = prv - cur;
    xxx[q] = fmaf(xx[q], tmx, cur);
  }

  float a0[4] = {0, 0, 0, 0}, a1[4] = {0, 0, 0, 0}, a2[4] = {0, 0, 0, 0};
#pragma unroll
  for (int c = 0; c < 64; ++c) {
    const float2 wv = w1a[c * 64 + j];
    const float wc = w1c[c * 32 + j32];
#pragma unroll
    for (int q = 0; q < 4; ++q) {
      const float s = rl(xxx[q], c);
      a0[q] = fmaf(s, wv.x, a0[q]);
      a1[q] = fmaf(s, wv.y, a1[q]);
      a2[q] = fmaf(s, wc, a2[q]);
    }
  }
#pragma unroll
  for (int q = 0; q < 4; ++q) {
    a0[q] = tanh_f(a0[q]); a1[q] = tanh_f(a1[q]); a2[q] = tanh_f(a2[q]);
  }

  // ---- phase 2: w2 ----
  __syncthreads();  // done reading w1
  for (int idx = tid; idx < 2048; idx += 512) {
    const int q = idx >> 6, jj = idx & 63;
    w2a[idx] = make_float4(maa_w2[q * 64 + jj], maa_w2[(32 + q) * 64 + jj],
                           maa_w2[(64 + q) * 64 + jj], maa_w2[(96 + q) * 64 + jj]);
    w2b[idx] = maa_w2[(128 + q) * 64 + jj];
  }
  __syncthreads();

  float m0[4] = {0,0,0,0}, m1[4] = {0,0,0,0}, m2[4] = {0,0,0,0},
        m3[4] = {0,0,0,0}, m4[4] = {0,0,0,0};
#pragma unroll
  for (int q2 = 0; q2 < 32; ++q2) {
    const float4 w4 = w2a[q2 * 64 + j];
    const float w5 = w2b[q2 * 64 + j];
#pragma unroll
    for (int q = 0; q < 4; ++q) {
      m0[q] = fmaf(rl(a0[q], q2),      w4.x, m0[q]);
      m1[q] = fmaf(rl(a0[q], 32 + q2), w4.y, m1[q]);
      m2[q] = fmaf(rl(a1[q], q2),      w4.z, m2[q]);
      m3[q] = fmaf(rl(a1[q], 32 + q2), w4.w, m3[q]);
      m4[q] = fmaf(rl(a2[q], q2),      w5,   m4[q]);
    }
  }
  float xw[4];
#pragma unroll
  for (int q = 0; q < 4; ++q) {
    const size_t o = (size_t)(bt0 + q) * CC + j;
    xw[q] = fmaf(xx[q], tmw + m0[q], xc[q]);   // kept in registers
    xk_o[o] = fmaf(xx[q], tmk + m1[q], xc[q]);
    xv_o[o] = fmaf(xx[q], tmv + m2[q], xc[q]);
    xr_o[o] = fmaf(xx[q], tmr + m3[q], xc[q]);
    xg_o[o] = fmaf(xx[q], tmg + m4[q], xc[q]);
  }

  // ---- phase 3: decay MLP ----
  __syncthreads();  // done reading w2
  for (int idx = tid; idx < 4096; idx += 512)
    decW[idx] = make_float2(dec_w1[idx], dec_w2[idx]);
  __syncthreads();

  const float td = t_decay[j];
  float hh[4] = {0,0,0,0};
#pragma unroll
  for (int c = 0; c < 64; ++c) {
    const float dw = decW[c * 64 + j].x;
#pragma unroll
    for (int q = 0; q < 4; ++q) hh[q] = fmaf(rl(xw[q], c), dw, hh[q]);
  }
#pragma unroll
  for (int q = 0; q < 4; ++q) hh[q] = tanh_f(hh[q]);

  float wf[4] = {td, td, td, td};
#pragma unroll
  for (int c = 0; c < 64; ++c) {
    const float dw = decW[c * 64 + j].y;
#pragma unroll
    for (int q = 0; q < 4; ++q) wf[q] = fmaf(rl(hh[q], c), dw, wf[q]);
  }
#pragma unroll
  for (int q = 0; q < 4; ++q)
    rkdc[4 * ((size_t)(bt0 + q) * CC + j) + 2] = __expf(-__expf(wf[q]));
}

// ---- proj4: r,k,v,g projections + ct (round-5/7 proven version) ----------
__global__ __launch_bounds__(512, 4) void proj4_kernel(
    const float* __restrict__ xk_i, const float* __restrict__ xv_i,
    const float* __restrict__ xr_i, const float* __restrict__ xg_i,
    const float* __restrict__ u,
    const float* __restrict__ Wr, const float* __restrict__ Wk, const float* __restrict__ Wv,
    const float* __restrict__ Wg,
    float* __restrict__ rkdc, float* __restrict__ v_o, float* __restrict__ g_o)
{
  __shared__ float4 projW[4096];   // {Wr^T, Wk^T, Wv^T, Wg^T}[c][j]
  const int tid = threadIdx.x;
  for (int idx = tid; idx < 4096; idx += 512) {
    const int c = idx >> 6, jj = idx & 63;
    projW[idx] = make_float4(Wr[jj * 64 + c], Wk[jj * 64 + c],
                             Wv[jj * 64 + c], Wg[jj * 64 + c]);
  }
  __syncthreads();

  const int w = tid >> 6, j = tid & 63;
  const int bt0 = blockIdx.x * 32 + w * 4;
  const float u_j = u[j];

  float xk[4], xv_[4], xr[4], xg[4];
#pragma unroll
  for (int q = 0; q < 4; ++q) {
    const size_t o = (size_t)(bt0 + q) * CC + j;
    xk[q] = xk_i[o]; xv_[q] = xv_i[o]; xr[q] = xr_i[o]; xg[q] = xg_i[o];
  }

  float ar[4] = {0,0,0,0}, ak[4] = {0,0,0,0}, av[4] = {0,0,0,0}, ag[4] = {0,0,0,0};
#pragma unroll
  for (int c = 0; c < 64; ++c) {
    const float4 wv = projW[c * 64 + j];
#pragma unroll
    for (int q = 0; q < 4; ++q) {
      ar[q] = fmaf(rl(xr[q], c),  wv.x, ar[q]);
      ak[q] = fmaf(rl(xk[q], c),  wv.y, ak[q]);
      av[q] = fmaf(rl(xv_[q], c), wv.z, av[q]);
      ag[q] = fmaf(rl(xg[q], c),  wv.w, ag[q]);
    }
  }

#pragma unroll
  for (int q = 0; q < 4; ++q) {
    const size_t o = (size_t)(bt0 + q) * CC + j;
    const float ct = wave_red_sum(ar[q] * u_j * ak[q]);  // sum_i r_i u_i k_i
    rkdc[4 * o + 0] = ar[q];
    rkdc[4 * o + 1] = ak[q];
    rkdc[4 * o + 3] = ct;
    v_o[o] = av[q];
    g_o[o] = ag[q] / (1.f + __expf(-ag[q]));  // silu
  }
}

// ---- A: chunk-local state. Wave = (b,ch); lane = j; S[i] in 64 VGPRs. ----
__global__ __launch_bounds__(256) void chunkA_kernel(
    const float4* __restrict__ rkdc, const float* __restrict__ v_i,
    float* __restrict__ Sloc, float* __restrict__ Dp)
{
  const int lane = threadIdx.x & 63;
  const int bch = __builtin_amdgcn_readfirstlane((blockIdx.x << 2) + (threadIdx.x >> 6));
  const float4* fq = rkdc + (size_t)bch * (CL * CC);       // [t][i]
  const float* dq = (const float*)fq + 4 * lane + 2;       // own d (i = lane)
  const float* vq = v_i + (size_t)bch * (CL * CC) + lane;  // v[t][j=lane]

  float S[CC];
#pragma unroll
  for (int i = 0; i < CC; ++i) S[i] = 0.f;
  float dp = 1.f;

  for (int t = 0; t < CL; ++t) {
    const float4* ft = fq + t * CC;
    const float vv = vq[t * CC];
    dp *= dq[4 * t * CC];
#pragma unroll
    for (int i = 0; i < CC; ++i) {
      const float4 f = ft[i];  // uniform address -> s_load
      S[i] = fmaf(f.z, S[i], f.y * vv);
    }
  }
  float* so = Sloc + (size_t)bch * (CC * CC) + lane;
#pragma unroll
  for (int i = 0; i < CC; ++i) so[i * CC] = S[i];
  Dp[(size_t)bch * CC + lane] = dp;
}

// ---- B: in-place combine over chunks: buf[bch] := S0 for that chunk ------
__global__ __launch_bounds__(1024) void combine_kernel(
    float* __restrict__ buf, const float* __restrict__ Dp)
{
  const int b = blockIdx.x, tid = threadIdx.x;
  __shared__ float sDp[NCH * CC];
  for (int idx = tid; idx < NCH * CC; idx += 1024)
    sDp[idx] = Dp[(size_t)b * NCH * CC + idx];
  __syncthreads();
  float run[4] = {0.f, 0.f, 0.f, 0.f};
  for (int ch = 0; ch < NCH; ++ch) {
    const size_t base = ((size_t)(b * NCH + ch)) * (CC * CC);
    const float* drow = sDp + ch * CC;
#pragma unroll
    for (int k2 = 0; k2 < 4; ++k2) {
      const int idx = tid + (k2 << 10);
      const float tmp = buf[base + idx];
      buf[base + idx] = run[k2];
      run[k2] = fmaf(run[k2], drow[idx >> 6], tmp);
    }
  }
}

// ---- C: emit + GroupNorm + *g + @Wo.T fused ------------------------------
__global__ __launch_bounds__(256) void scanC_kernel(
    const float4* __restrict__ rkdc, const float* __restrict__ v_i,
    const float* __restrict__ S0, const float* __restrict__ g_i,
    const float* __restrict__ ln_w, const float* __restrict__ ln_b,
    const float* __restrict__ Wo, float* __restrict__ out)
{
  __shared__ float WoT[4096];  // Wo^T[c][j] 16KB
  for (int idx = threadIdx.x; idx < 4096; idx += 256) {
    const int c = idx >> 6, jj = idx & 63;
    WoT[idx] = Wo[jj * 64 + c];
  }
  __syncthreads();

  const int lane = threadIdx.x & 63;
  const int bch = __builtin_amdgcn_readfirstlane((blockIdx.x << 2) + (threadIdx.x >> 6));
  const float4* fq = rkdc + (size_t)bch * (CL * CC);
  const float* vq = v_i + (size_t)bch * (CL * CC) + lane;
  const float* gq = g_i + (size_t)bch * (CL * CC) + lane;
  float* oq = out + (size_t)bch * (CL * CC) + lane;
  const float lnw = ln_w[lane], lnb = ln_b[lane];

  float S[CC];
  const float* si = S0 + (size_t)bch * (CC * CC) + lane;
#pragma unroll
  for (int i = 0; i < CC; ++i) S[i] = si[i * CC];

  for (int t = 0; t < CL; ++t) {
    const float4* ft = fq + t * CC;
    const float vv = vq[t * CC];
    float y0, y1;
    {
      const float4 f = ft[0];
      y0 = fmaf(f.x, S[0], f.w * vv);  // f.w = ct (uniform), y uses OLD S
      S[0] = fmaf(f.z, S[0], f.y * vv);
    }
    {
      const float4 f = ft[1];
      y1 = f.x * S[1];
      S[1] = fmaf(f.z, S[1], f.y * vv);
    }
#pragma unroll
    for (int i = 2; i < CC; i += 2) {
      const float4 fa = ft[i];
      y0 = fmaf(fa.x, S[i], y0);
      S[i] = fmaf(fa.z, S[i], fa.y * vv);
      const float4 fb = ft[i + 1];
      y1 = fmaf(fb.x, S[i + 1], y1);
      S[i + 1] = fmaf(fb.z, S[i + 1], fb.y * vv);
    }
    const float y = y0 + y1;  // y[t][lane]

    // GroupNorm(64) across lanes + silu(g) + Wo matvec
    const float s1 = wave_red_sum(y);
    const float s2 = wave_red_sum(y * y);
    const float mu = s1 * (1.f / CC);
    const float var = s2 * (1.f / CC) - mu * mu;
    const float z = (y - mu) * rsqrtf(var + GN_EPS) * lnw + lnb;
    const float sz = z * gq[t * CC];
    float acc = 0.f;
#pragma unroll
    for (int c = 0; c < CC; ++c) acc = fmaf(rl(sz, c), WoT[c * 64 + lane], acc);
    oq[t * CC] = acc;
  }
}

extern "C" void kernel_launch(void* const* d_in, const int* in_sizes, int n_in,
                              void* d_out, int out_size, void* d_ws, size_t ws_size,
                              hipStream_t stream) {
  const float* x       = (const float*)d_in[0];
  const float* tm_x    = (const float*)d_in[1];
  const float* tm_w    = (const float*)d_in[2];
  const float* tm_k    = (const float*)d_in[3];
  const float* tm_v    = (const float*)d_in[4];
  const float* tm_r    = (const float*)d_in[5];
  const float* tm_g    = (const float*)d_in[6];
  const float* maa_w1  = (const float*)d_in[7];
  const float* maa_w2  = (const float*)d_in[8];
  const float* t_decay = (const float*)d_in[9];
  const float* dec_w1  = (const float*)d_in[10];
  const float* dec_w2  = (const float*)d_in[11];
  const float* u       = (const float*)d_in[12];
  const float* Wr      = (const float*)d_in[13];
  const float* Wk      = (const float*)d_in[14];
  const float* Wv      = (const float*)d_in[15];
  const float* Wg      = (const float*)d_in[16];
  const float* Wo      = (const float*)d_in[17];
  const float* ln_w    = (const float*)d_in[18];
  const float* ln_b    = (const float*)d_in[19];

  const size_t M = (size_t)BT * CC;  // 4.19M floats
  float* ws   = (float*)d_ws;
  float* xk_o = ws;                  // [0,M)   dead after proj4
  float* xv_o = ws + M;              // [M,2M)  dead after proj4
  float* xr_o = ws + 2 * M;          // [2M,3M) dead after proj4
  float* xg_o = ws + 3 * M;          // [3M,4M) dead after proj4
  float* g_o  = ws + 4 * M;          // alive until scanC
  float* v_o  = ws + 5 * M;          // alive until scanC
  float* rkdc = ws + 6 * M;          // [6M,10M) float4 stream
  float* scb  = ws;                  // Sloc==S0 (in-place), 2M floats
  float* Dp   = ws + 2 * M;          // B*NCH*CC floats (aliases dead xr_o)
  float* out  = (float*)d_out;       // final output only

  mix_kernel<<<2048, 512, 0, stream>>>(
      x, tm_x, tm_w, tm_k, tm_v, tm_r, tm_g, maa_w1, maa_w2,
      t_decay, dec_w1, dec_w2,
      xk_o, xv_o, xr_o, xg_o, rkdc);

  proj4_kernel<<<2048, 512, 0, stream>>>(
      xk_o, xv_o, xr_o, xg_o, u, Wr, Wk, Wv, Wg, rkdc, v_o, g_o);

  chunkA_kernel<<<(BB * NCH) / 4, 256, 0, stream>>>(
      (const float4*)rkdc, v_o, scb, Dp);

  combine_kernel<<<BB, 1024, 0, stream>>>(scb, Dp);

  scanC_kernel<<<(BB * NCH) / 4, 256, 0, stream>>>(
      (const float4*)rkdc, v_o, scb, g_o, ln_w, ln_b, Wo, out);
}

// Round 12
// 393.255 us; speedup vs baseline: 4.9624x; 1.1368x over previous
//
#include <hip/hip_runtime.h>

#define BB 32
#define TT 2048
#define CC 64
#define BT (BB * TT)
#define NCH 64
#define CL 32  // chunk length; NCH*CL == TT
#define GN_EPS (1e-5f * 64.f)

typedef short short8 __attribute__((ext_vector_type(8)));
typedef float f32x4 __attribute__((ext_vector_type(4)));

// ---- cross-lane helpers --------------------------------------------------
__device__ __forceinline__ float rl(float v, int lane) {
  return __uint_as_float(__builtin_amdgcn_readlane(__float_as_uint(v), lane));
}
template <int CTRL>
__device__ __forceinline__ float dppadd(float x) {
  return x + __int_as_float(__builtin_amdgcn_update_dpp(
                 0, __float_as_int(x), CTRL, 0xf, 0xf, true));
}
// Full wave64 sum -> broadcast.
__device__ __forceinline__ float wave_red_sum(float x) {
  x = dppadd<0x111>(x);  // row_shr:1
  x = dppadd<0x112>(x);  // row_shr:2
  x = dppadd<0x114>(x);  // row_shr:4
  x = dppadd<0x118>(x);  // row_shr:8
  x = dppadd<0x142>(x);  // row_bcast:15
  x = dppadd<0x143>(x);  // row_bcast:31
  return __uint_as_float(__builtin_amdgcn_readlane(__float_as_uint(x), 63));
}
__device__ __forceinline__ float tanh_f(float x) {
  x = fminf(fmaxf(x, -10.f), 10.f);
  const float e = __expf(2.f * x);
  return (e - 1.f) / (e + 1.f);
}

// ---- bf16 split helpers --------------------------------------------------
__device__ __forceinline__ unsigned short f2bf(float x) {
  unsigned int u = __float_as_uint(x);
  u += 0x7FFFu + ((u >> 16) & 1u);   // RNE
  return (unsigned short)(u >> 16);
}
__device__ __forceinline__ float bf2f(unsigned short h) {
  return __uint_as_float(((unsigned int)h) << 16);
}

// ---- mix: token-shift + maa mixing + decay MLP; LDS phased 40KB ----------
__global__ __launch_bounds__(512, 4) void mix_kernel(
    const float* __restrict__ x,
    const float* __restrict__ tm_x, const float* __restrict__ tm_w, const float* __restrict__ tm_k,
    const float* __restrict__ tm_v, const float* __restrict__ tm_r, const float* __restrict__ tm_g,
    const float* __restrict__ maa_w1, const float* __restrict__ maa_w2,
    const float* __restrict__ t_decay, const float* __restrict__ dec_w1,
    const float* __restrict__ dec_w2,
    float* __restrict__ xk_o, float* __restrict__ xv_o,
    float* __restrict__ xr_o, float* __restrict__ xg_o,
    float* __restrict__ rkdc)
{
  __shared__ float lds[10240];              // 40KB, reused across 3 phases
  float2* w1a = (float2*)lds;               // phase1: 4096 float2
  float*  w1c = lds + 8192;                 //         2048 floats
  float4* w2a = (float4*)lds;               // phase2: 2048 float4
  float*  w2b = lds + 8192;                 //         2048 floats
  float2* decW = (float2*)lds;              // phase3: 4096 float2

  const int tid = threadIdx.x;
  // ---- phase 1: w1 ----
  for (int idx = tid; idx < 4096; idx += 512) {
    const int c = idx >> 6, jj = idx & 63;
    w1a[idx] = make_float2(maa_w1[c * 160 + jj], maa_w1[c * 160 + 64 + jj]);
  }
  for (int idx = tid; idx < 2048; idx += 512) {
    const int c = idx >> 5, jj = idx & 31;
    w1c[idx] = maa_w1[c * 160 + 128 + jj];
  }
  __syncthreads();

  const int w = tid >> 6, j = tid & 63;
  const int j32 = j & 31;
  const int bt0 = blockIdx.x * 32 + w * 4;
  const float tmx = tm_x[j], tmw = tm_w[j], tmk = tm_k[j],
              tmv = tm_v[j], tmr = tm_r[j], tmg = tm_g[j];

  float xc[4], xx[4], xxx[4];
#pragma unroll
  for (int q = 0; q < 4; ++q) {
    const int bt = bt0 + q;
    const int t = bt & (TT - 1);
    const float cur = x[(size_t)bt * CC + j];
    const float prv = (t != 0) ? x[(size_t)(bt - 1) * CC + j] : 0.f;
    xc[q] = cur;
    xx[q] = prv - cur;
    xxx[q] = fmaf(xx[q], tmx, cur);
  }

  float a0[4] = {0, 0, 0, 0}, a1[4] = {0, 0, 0, 0}, a2[4] = {0, 0, 0, 0};
#pragma unroll
  for (int c = 0; c < 64; ++c) {
    const float2 wv = w1a[c * 64 + j];
    const float wc = w1c[c * 32 + j32];
#pragma unroll
    for (int q = 0; q < 4; ++q) {
      const float s = rl(xxx[q], c);
      a0[q] = fmaf(s, wv.x, a0[q]);
      a1[q] = fmaf(s, wv.y, a1[q]);
      a2[q] = fmaf(s, wc, a2[q]);
    }
  }
#pragma unroll
  for (int q = 0; q < 4; ++q) {
    a0[q] = tanh_f(a0[q]); a1[q] = tanh_f(a1[q]); a2[q] = tanh_f(a2[q]);
  }

  // ---- phase 2: w2 ----
  __syncthreads();  // done reading w1
  for (int idx = tid; idx < 2048; idx += 512) {
    const int q = idx >> 6, jj = idx & 63;
    w2a[idx] = make_float4(maa_w2[q * 64 + jj], maa_w2[(32 + q) * 64 + jj],
                           maa_w2[(64 + q) * 64 + jj], maa_w2[(96 + q) * 64 + jj]);
    w2b[idx] = maa_w2[(128 + q) * 64 + jj];
  }
  __syncthreads();

  float m0[4] = {0,0,0,0}, m1[4] = {0,0,0,0}, m2[4] = {0,0,0,0},
        m3[4] = {0,0,0,0}, m4[4] = {0,0,0,0};
#pragma unroll
  for (int q2 = 0; q2 < 32; ++q2) {
    const float4 w4 = w2a[q2 * 64 + j];
    const float w5 = w2b[q2 * 64 + j];
#pragma unroll
    for (int q = 0; q < 4; ++q) {
      m0[q] = fmaf(rl(a0[q], q2),      w4.x, m0[q]);
      m1[q] = fmaf(rl(a0[q], 32 + q2), w4.y, m1[q]);
      m2[q] = fmaf(rl(a1[q], q2),      w4.z, m2[q]);
      m3[q] = fmaf(rl(a1[q], 32 + q2), w4.w, m3[q]);
      m4[q] = fmaf(rl(a2[q], q2),      w5,   m4[q]);
    }
  }
  float xw[4];
#pragma unroll
  for (int q = 0; q < 4; ++q) {
    const size_t o = (size_t)(bt0 + q) * CC + j;
    xw[q] = fmaf(xx[q], tmw + m0[q], xc[q]);   // kept in registers
    xk_o[o] = fmaf(xx[q], tmk + m1[q], xc[q]);
    xv_o[o] = fmaf(xx[q], tmv + m2[q], xc[q]);
    xr_o[o] = fmaf(xx[q], tmr + m3[q], xc[q]);
    xg_o[o] = fmaf(xx[q], tmg + m4[q], xc[q]);
  }

  // ---- phase 3: decay MLP ----
  __syncthreads();  // done reading w2
  for (int idx = tid; idx < 4096; idx += 512)
    decW[idx] = make_float2(dec_w1[idx], dec_w2[idx]);
  __syncthreads();

  const float td = t_decay[j];
  float hh[4] = {0,0,0,0};
#pragma unroll
  for (int c = 0; c < 64; ++c) {
    const float dw = decW[c * 64 + j].x;
#pragma unroll
    for (int q = 0; q < 4; ++q) hh[q] = fmaf(rl(xw[q], c), dw, hh[q]);
  }
#pragma unroll
  for (int q = 0; q < 4; ++q) hh[q] = tanh_f(hh[q]);

  float wf[4] = {td, td, td, td};
#pragma unroll
  for (int c = 0; c < 64; ++c) {
    const float dw = decW[c * 64 + j].y;
#pragma unroll
    for (int q = 0; q < 4; ++q) wf[q] = fmaf(rl(hh[q], c), dw, wf[q]);
  }
#pragma unroll
  for (int q = 0; q < 4; ++q)
    rkdc[4 * ((size_t)(bt0 + q) * CC + j) + 2] = __expf(-__expf(wf[q]));
}

// ---- proj4 via MFMA (bf16 3-product split) -------------------------------
// Wave = 32 tokens x 64 outputs. A: lane covers row=l&15, k=(l>>4)*8+r.
// B[k][n]: col=l&15 (=j), k=(l>>4)*8+r -> contiguous row of W.
// C/D: col=l&15, row=(l>>4)*4+reg  [verified mapping].
__device__ __forceinline__ void load_afrag(
    const float* __restrict__ X, int tok0, int col, int half,
    short8 ah[2][2], short8 al[2][2])
{
#pragma unroll
  for (int m = 0; m < 2; ++m)
#pragma unroll
    for (int kk = 0; kk < 2; ++kk) {
      const float* p = X + (size_t)(tok0 + m * 16 + col) * CC + kk * 32 + half * 8;
      const float4 v0 = *reinterpret_cast<const float4*>(p);
      const float4 v1 = *reinterpret_cast<const float4*>(p + 4);
      const float vv[8] = {v0.x, v0.y, v0.z, v0.w, v1.x, v1.y, v1.z, v1.w};
      short8 h, l;
#pragma unroll
      for (int e = 0; e < 8; ++e) {
        const unsigned short hb = f2bf(vv[e]);
        h[e] = (short)hb;
        l[e] = (short)f2bf(vv[e] - bf2f(hb));
      }
      ah[m][kk] = h; al[m][kk] = l;
    }
}
__device__ __forceinline__ void load_bfrag(
    const float* __restrict__ W, int col, int half,
    short8 bh[4][2], short8 bl[4][2])
{
#pragma unroll
  for (int n = 0; n < 4; ++n)
#pragma unroll
    for (int kk = 0; kk < 2; ++kk) {
      const float* p = W + (size_t)(n * 16 + col) * CC + kk * 32 + half * 8;
      const float4 v0 = *reinterpret_cast<const float4*>(p);
      const float4 v1 = *reinterpret_cast<const float4*>(p + 4);
      const float vv[8] = {v0.x, v0.y, v0.z, v0.w, v1.x, v1.y, v1.z, v1.w};
      short8 h, l;
#pragma unroll
      for (int e = 0; e < 8; ++e) {
        const unsigned short hb = f2bf(vv[e]);
        h[e] = (short)hb;
        l[e] = (short)f2bf(vv[e] - bf2f(hb));
      }
      bh[n][kk] = h; bl[n][kk] = l;
    }
}
__device__ __forceinline__ void gemm_acc(
    const short8 ah[2][2], const short8 al[2][2],
    const short8 bh[4][2], const short8 bl[4][2], f32x4 acc[2][4])
{
#pragma unroll
  for (int m = 0; m < 2; ++m)
#pragma unroll
    for (int n = 0; n < 4; ++n) {
      f32x4 a = acc[m][n];
#pragma unroll
      for (int kk = 0; kk < 2; ++kk) {
        a = __builtin_amdgcn_mfma_f32_16x16x32_bf16(ah[m][kk], bh[n][kk], a, 0, 0, 0);
        a = __builtin_amdgcn_mfma_f32_16x16x32_bf16(ah[m][kk], bl[n][kk], a, 0, 0, 0);
        a = __builtin_amdgcn_mfma_f32_16x16x32_bf16(al[m][kk], bh[n][kk], a, 0, 0, 0);
      }
      acc[m][n] = a;
    }
}

__global__ __launch_bounds__(256) void proj4_mfma_kernel(
    const float* __restrict__ xk_i, const float* __restrict__ xv_i,
    const float* __restrict__ xr_i, const float* __restrict__ xg_i,
    const float* __restrict__ u,
    const float* __restrict__ Wr, const float* __restrict__ Wk, const float* __restrict__ Wv,
    const float* __restrict__ Wg,
    float* __restrict__ rkdc, float* __restrict__ v_o, float* __restrict__ g_o)
{
  const int lane = threadIdx.x & 63;
  const int wid = threadIdx.x >> 6;
  const int col = lane & 15, half = lane >> 4;
  const int tok0 = blockIdx.x * 128 + wid * 32;

  short8 ah[2][2], al[2][2], bh[4][2], bl[4][2];
  f32x4 accr[2][4], acck[2][4];

  // ---- r = xr @ Wr^T ----
  load_bfrag(Wr, col, half, bh, bl);
  load_afrag(xr_i, tok0, col, half, ah, al);
#pragma unroll
  for (int m = 0; m < 2; ++m)
#pragma unroll
    for (int n = 0; n < 4; ++n) accr[m][n] = (f32x4){0.f, 0.f, 0.f, 0.f};
  gemm_acc(ah, al, bh, bl, accr);

  // ---- k = xk @ Wk^T ----
  load_bfrag(Wk, col, half, bh, bl);
  load_afrag(xk_i, tok0, col, half, ah, al);
#pragma unroll
  for (int m = 0; m < 2; ++m)
#pragma unroll
    for (int n = 0; n < 4; ++n) acck[m][n] = (f32x4){0.f, 0.f, 0.f, 0.f};
  gemm_acc(ah, al, bh, bl, acck);

  // ---- ct[token] = sum_j r*u*k : in-thread over n, 16-lane reduce over col
  float uv[4];
#pragma unroll
  for (int n = 0; n < 4; ++n) uv[n] = u[n * 16 + col];
  float ctv[2][4];
#pragma unroll
  for (int m = 0; m < 2; ++m)
#pragma unroll
    for (int reg = 0; reg < 4; ++reg) {
      float p = 0.f;
#pragma unroll
      for (int n = 0; n < 4; ++n)
        p += accr[m][n][reg] * uv[n] * acck[m][n][reg];
      p += __shfl_xor(p, 1, 64);
      p += __shfl_xor(p, 2, 64);
      p += __shfl_xor(p, 4, 64);
      p += __shfl_xor(p, 8, 64);
      ctv[m][reg] = p;
    }

  // ---- write r, k, ct into rkdc ----
#pragma unroll
  for (int m = 0; m < 2; ++m)
#pragma unroll
    for (int n = 0; n < 4; ++n)
#pragma unroll
      for (int reg = 0; reg < 4; ++reg) {
        const int token = tok0 + m * 16 + half * 4 + reg;
        const size_t o = (size_t)token * CC + n * 16 + col;
        rkdc[4 * o + 0] = accr[m][n][reg];
        rkdc[4 * o + 1] = acck[m][n][reg];
        rkdc[4 * o + 3] = ctv[m][reg];
      }

  // ---- v = xv @ Wv^T ----
  load_bfrag(Wv, col, half, bh, bl);
  load_afrag(xv_i, tok0, col, half, ah, al);
#pragma unroll
  for (int m = 0; m < 2; ++m)
#pragma unroll
    for (int n = 0; n < 4; ++n) accr[m][n] = (f32x4){0.f, 0.f, 0.f, 0.f};
  gemm_acc(ah, al, bh, bl, accr);
#pragma unroll
  for (int m = 0; m < 2; ++m)
#pragma unroll
    for (int n = 0; n < 4; ++n)
#pragma unroll
      for (int reg = 0; reg < 4; ++reg) {
        const int token = tok0 + m * 16 + half * 4 + reg;
        v_o[(size_t)token * CC + n * 16 + col] = accr[m][n][reg];
      }

  // ---- g = silu(xg @ Wg^T) ----
  load_bfrag(Wg, col, half, bh, bl);
  load_afrag(xg_i, tok0, col, half, ah, al);
#pragma unroll
  for (int m = 0; m < 2; ++m)
#pragma unroll
    for (int n = 0; n < 4; ++n) accr[m][n] = (f32x4){0.f, 0.f, 0.f, 0.f};
  gemm_acc(ah, al, bh, bl, accr);
#pragma unroll
  for (int m = 0; m < 2; ++m)
#pragma unroll
    for (int n = 0; n < 4; ++n)
#pragma unroll
      for (int reg = 0; reg < 4; ++reg) {
        const int token = tok0 + m * 16 + half * 4 + reg;
        const float gg = accr[m][n][reg];
        g_o[(size_t)token * CC + n * 16 + col] = gg / (1.f + __expf(-gg));
      }
}

// ---- A: chunk-local state. Wave = (b,ch); lane = j; S[i] in 64 VGPRs. ----
__global__ __launch_bounds__(256) void chunkA_kernel(
    const float4* __restrict__ rkdc, const float* __restrict__ v_i,
    float* __restrict__ Sloc, float* __restrict__ Dp)
{
  const int lane = threadIdx.x & 63;
  const int bch = __builtin_amdgcn_readfirstlane((blockIdx.x << 2) + (threadIdx.x >> 6));
  const float4* fq = rkdc + (size_t)bch * (CL * CC);       // [t][i]
  const float* dq = (const float*)fq + 4 * lane + 2;       // own d (i = lane)
  const float* vq = v_i + (size_t)bch * (CL * CC) + lane;  // v[t][j=lane]

  float S[CC];
#pragma unroll
  for (int i = 0; i < CC; ++i) S[i] = 0.f;
  float dp = 1.f;

  for (int t = 0; t < CL; ++t) {
    const float4* ft = fq + t * CC;
    const float vv = vq[t * CC];
    dp *= dq[4 * t * CC];
#pragma unroll
    for (int i = 0; i < CC; ++i) {
      const float4 f = ft[i];  // uniform address -> s_load
      S[i] = fmaf(f.z, S[i], f.y * vv);
    }
  }
  float* so = Sloc + (size_t)bch * (CC * CC) + lane;
#pragma unroll
  for (int i = 0; i < CC; ++i) so[i * CC] = S[i];
  Dp[(size_t)bch * CC + lane] = dp;
}

// ---- B: in-place combine over chunks: buf[bch] := S0 for that chunk ------
__global__ __launch_bounds__(1024) void combine_kernel(
    float* __restrict__ buf, const float* __restrict__ Dp)
{
  const int b = blockIdx.x, tid = threadIdx.x;
  __shared__ float sDp[NCH * CC];
  for (int idx = tid; idx < NCH * CC; idx += 1024)
    sDp[idx] = Dp[(size_t)b * NCH * CC + idx];
  __syncthreads();
  float run[4] = {0.f, 0.f, 0.f, 0.f};
  for (int ch = 0; ch < NCH; ++ch) {
    const size_t base = ((size_t)(b * NCH + ch)) * (CC * CC);
    const float* drow = sDp + ch * CC;
#pragma unroll
    for (int k2 = 0; k2 < 4; ++k2) {
      const int idx = tid + (k2 << 10);
      const float tmp = buf[base + idx];
      buf[base + idx] = run[k2];
      run[k2] = fmaf(run[k2], drow[idx >> 6], tmp);
    }
  }
}

// ---- C: emit + GroupNorm + *g + @Wo.T fused ------------------------------
__global__ __launch_bounds__(256) void scanC_kernel(
    const float4* __restrict__ rkdc, const float* __restrict__ v_i,
    const float* __restrict__ S0, const float* __restrict__ g_i,
    const float* __restrict__ ln_w, const float* __restrict__ ln_b,
    const float* __restrict__ Wo, float* __restrict__ out)
{
  __shared__ float WoT[4096];  // Wo^T[c][j] 16KB
  for (int idx = threadIdx.x; idx < 4096; idx += 256) {
    const int c = idx >> 6, jj = idx & 63;
    WoT[idx] = Wo[jj * 64 + c];
  }
  __syncthreads();

  const int lane = threadIdx.x & 63;
  const int bch = __builtin_amdgcn_readfirstlane((blockIdx.x << 2) + (threadIdx.x >> 6));
  const float4* fq = rkdc + (size_t)bch * (CL * CC);
  const float* vq = v_i + (size_t)bch * (CL * CC) + lane;
  const float* gq = g_i + (size_t)bch * (CL * CC) + lane;
  float* oq = out + (size_t)bch * (CL * CC) + lane;
  const float lnw = ln_w[lane], lnb = ln_b[lane];

  float S[CC];
  const float* si = S0 + (size_t)bch * (CC * CC) + lane;
#pragma unroll
  for (int i = 0; i < CC; ++i) S[i] = si[i * CC];

  for (int t = 0; t < CL; ++t) {
    const float4* ft = fq + t * CC;
    const float vv = vq[t * CC];
    float y0, y1;
    {
      const float4 f = ft[0];
      y0 = fmaf(f.x, S[0], f.w * vv);  // f.w = ct (uniform), y uses OLD S
      S[0] = fmaf(f.z, S[0], f.y * vv);
    }
    {
      const float4 f = ft[1];
      y1 = f.x * S[1];
      S[1] = fmaf(f.z, S[1], f.y * vv);
    }
#pragma unroll
    for (int i = 2; i < CC; i += 2) {
      const float4 fa = ft[i];
      y0 = fmaf(fa.x, S[i], y0);
      S[i] = fmaf(fa.z, S[i], fa.y * vv);
      const float4 fb = ft[i + 1];
      y1 = fmaf(fb.x, S[i + 1], y1);
      S[i + 1] = fmaf(fb.z, S[i + 1], fb.y * vv);
    }
    const float y = y0 + y1;  // y[t][lane]

    // GroupNorm(64) across lanes + silu(g) + Wo matvec
    const float s1 = wave_red_sum(y);
    const float s2 = wave_red_sum(y * y);
    const float mu = s1 * (1.f / CC);
    const float var = s2 * (1.f / CC) - mu * mu;
    const float z = (y - mu) * rsqrtf(var + GN_EPS) * lnw + lnb;
    const float sz = z * gq[t * CC];
    float acc = 0.f;
#pragma unroll
    for (int c = 0; c < CC; ++c) acc = fmaf(rl(sz, c), WoT[c * 64 + lane], acc);
    oq[t * CC] = acc;
  }
}

extern "C" void kernel_launch(void* const* d_in, const int* in_sizes, int n_in,
                              void* d_out, int out_size, void* d_ws, size_t ws_size,
                              hipStream_t stream) {
  const float* x       = (const float*)d_in[0];
  const float* tm_x    = (const float*)d_in[1];
  const float* tm_w    = (const float*)d_in[2];
  const float* tm_k    = (const float*)d_in[3];
  const float* tm_v    = (const float*)d_in[4];
  const float* tm_r    = (const float*)d_in[5];
  const float* tm_g    = (const float*)d_in[6];
  const float* maa_w1  = (const float*)d_in[7];
  const float* maa_w2  = (const float*)d_in[8];
  const float* t_decay = (const float*)d_in[9];
  const float* dec_w1  = (const float*)d_in[10];
  const float* dec_w2  = (const float*)d_in[11];
  const float* u       = (const float*)d_in[12];
  const float* Wr      = (const float*)d_in[13];
  const float* Wk      = (const float*)d_in[14];
  const float* Wv      = (const float*)d_in[15];
  const float* Wg      = (const float*)d_in[16];
  const float* Wo      = (const float*)d_in[17];
  const float* ln_w    = (const float*)d_in[18];
  const float* ln_b    = (const float*)d_in[19];

  const size_t M = (size_t)BT * CC;  // 4.19M floats
  float* ws   = (float*)d_ws;
  float* xk_o = ws;                  // [0,M)   dead after proj4
  float* xv_o = ws + M;              // [M,2M)  dead after proj4
  float* xr_o = ws + 2 * M;          // [2M,3M) dead after proj4
  float* xg_o = ws + 3 * M;          // [3M,4M) dead after proj4
  float* g_o  = ws + 4 * M;          // alive until scanC
  float* v_o  = ws + 5 * M;          // alive until scanC
  float* rkdc = ws + 6 * M;          // [6M,10M) float4 stream
  float* scb  = ws;                  // Sloc==S0 (in-place), 2M floats
  float* Dp   = ws + 2 * M;          // B*NCH*CC floats (aliases dead xr_o)
  float* out  = (float*)d_out;       // final output only

  mix_kernel<<<2048, 512, 0, stream>>>(
      x, tm_x, tm_w, tm_k, tm_v, tm_r, tm_g, maa_w1, maa_w2,
      t_decay, dec_w1, dec_w2,
      xk_o, xv_o, xr_o, xg_o, rkdc);

  proj4_mfma_kernel<<<BT / 128, 256, 0, stream>>>(
      xk_o, xv_o, xr_o, xg_o, u, Wr, Wk, Wv, Wg, rkdc, v_o, g_o);

  chunkA_kernel<<<(BB * NCH) / 4, 256, 0, stream>>>(
      (const float4*)rkdc, v_o, scb, Dp);

  combine_kernel<<<BB, 1024, 0, stream>>>(scb, Dp);

  scanC_kernel<<<(BB * NCH) / 4, 256, 0, stream>>>(
      (const float4*)rkdc, v_o, scb, g_o, ln_w, ln_b, Wo, out);
}

// Round 13
// 319.095 us; speedup vs baseline: 6.1157x; 1.2324x over previous
//
#include <hip/hip_runtime.h>

#define BB 32
#define TT 2048
#define CC 64
#define BT (BB * TT)
#define NCH 64
#define CL 32  // chunk length; NCH*CL == TT
#define GN_EPS (1e-5f * 64.f)

typedef short short8 __attribute__((ext_vector_type(8)));
typedef float f32x4 __attribute__((ext_vector_type(4)));

// ---- cross-lane helpers --------------------------------------------------
__device__ __forceinline__ float rl(float v, int lane) {
  return __uint_as_float(__builtin_amdgcn_readlane(__float_as_uint(v), lane));
}
template <int CTRL>
__device__ __forceinline__ float dppadd(float x) {
  return x + __int_as_float(__builtin_amdgcn_update_dpp(
                 0, __float_as_int(x), CTRL, 0xf, 0xf, true));
}
__device__ __forceinline__ float wave_red_sum(float x) {
  x = dppadd<0x111>(x);
  x = dppadd<0x112>(x);
  x = dppadd<0x114>(x);
  x = dppadd<0x118>(x);
  x = dppadd<0x142>(x);
  x = dppadd<0x143>(x);
  return __uint_as_float(__builtin_amdgcn_readlane(__float_as_uint(x), 63));
}
__device__ __forceinline__ float tanh_f(float x) {
  x = fminf(fmaxf(x, -10.f), 10.f);
  const float e = __expf(2.f * x);
  return (e - 1.f) / (e + 1.f);
}

// ---- bf16 helpers --------------------------------------------------------
__device__ __forceinline__ unsigned short f2bf(float x) {
  unsigned int u = __float_as_uint(x);
  u += 0x7FFFu + ((u >> 16) & 1u);   // RNE
  return (unsigned short)(u >> 16);
}
__device__ __forceinline__ float bf2f(unsigned short h) {
  return __uint_as_float(((unsigned int)h) << 16);
}
__device__ __forceinline__ short8 cvt8(const float4 a, const float4 b) {
  short8 h;
  h[0] = (short)f2bf(a.x); h[1] = (short)f2bf(a.y);
  h[2] = (short)f2bf(a.z); h[3] = (short)f2bf(a.w);
  h[4] = (short)f2bf(b.x); h[5] = (short)f2bf(b.y);
  h[6] = (short)f2bf(b.z); h[7] = (short)f2bf(b.w);
  return h;
}
__device__ __forceinline__ short8 ldb8(const float* __restrict__ p) {
  const float4 v0 = *reinterpret_cast<const float4*>(p);
  const float4 v1 = *reinterpret_cast<const float4*>(p + 4);
  return cvt8(v0, v1);
}
__device__ __forceinline__ short8 ldb8_lds(const float* p) {
  const float4 v0 = *reinterpret_cast<const float4*>(p);
  const float4 v1 = *reinterpret_cast<const float4*>(p + 4);
  return cvt8(v0, v1);
}

// ---- preT: transpose tiny weights for contiguous B-fragments -------------
__global__ __launch_bounds__(256) void preT_kernel(
    const float* __restrict__ maa_w1, const float* __restrict__ maa_w2,
    const float* __restrict__ dec_w1, const float* __restrict__ dec_w2,
    float* __restrict__ w1T, float* __restrict__ w2T,
    float* __restrict__ d1T, float* __restrict__ d2T)
{
  const int t0 = blockIdx.x * 256 + threadIdx.x;
  const int stride = gridDim.x * 256;
  for (int i = t0; i < 160 * 64; i += stride) {
    const int n = i >> 6, c = i & 63;
    w1T[i] = maa_w1[c * 160 + n];               // w1T[n][c]
  }
  for (int i = t0; i < 5 * 64 * 32; i += stride) {
    const int f = i >> 11, rem = i & 2047, n = rem >> 5, q = rem & 31;
    w2T[i] = maa_w2[(f * 32 + q) * 64 + n];     // w2T[f][n][q]
  }
  for (int i = t0; i < 4096; i += stride) {
    const int n = i >> 6, c = i & 63;
    d1T[i] = dec_w1[c * 64 + n];                // d1T[n][c]
    d2T[i] = dec_w2[c * 64 + n];                // d2T[n][q]
  }
}

// ---- mix via MFMA: token-shift + maa mixing + decay MLP ------------------
// Wave = 32 tokens. bf16 single-product (maa/dec weights are O(1e-4):
// mixing terms are O(1e-7) corrections -> bf16 rounding contributes ~1e-9).
#define LDS_A 36
#define LDS_X 68
__global__ __launch_bounds__(256) void mix_mfma_kernel(
    const float* __restrict__ x,
    const float* __restrict__ tm_x, const float* __restrict__ tm_w, const float* __restrict__ tm_k,
    const float* __restrict__ tm_v, const float* __restrict__ tm_r, const float* __restrict__ tm_g,
    const float* __restrict__ w1T, const float* __restrict__ w2T,
    const float* __restrict__ d1T, const float* __restrict__ d2T,
    const float* __restrict__ t_decay,
    float* __restrict__ xk_o, float* __restrict__ xv_o,
    float* __restrict__ xr_o, float* __restrict__ xg_o,
    float* __restrict__ rkdc)
{
  __shared__ float aT[4][32][LDS_A];   // per-wave a-transpose (32x32 used)
  __shared__ float xT[4][32][LDS_X];   // per-wave xw / h transpose (32x64)
  const int lane = threadIdx.x & 63;
  const int wid = threadIdx.x >> 6;
  const int col = lane & 15, half = lane >> 4;
  const int tok0 = blockIdx.x * 128 + wid * 32;

  // ---- A-layout xxx bf16 fragments (row=l&15, k=(l>>4)*8+e) ----
  short8 xa[2][2];
#pragma unroll
  for (int m = 0; m < 2; ++m)
#pragma unroll
    for (int kk = 0; kk < 2; ++kk) {
      const int tok = tok0 + m * 16 + col;
      const int kb = kk * 32 + half * 8;
      const float* pc = x + (size_t)tok * CC + kb;
      const float4 c0 = *reinterpret_cast<const float4*>(pc);
      const float4 c1 = *reinterpret_cast<const float4*>(pc + 4);
      float4 p0 = {0.f, 0.f, 0.f, 0.f}, p1 = {0.f, 0.f, 0.f, 0.f};
      if ((tok & (TT - 1)) != 0) {
        p0 = *reinterpret_cast<const float4*>(pc - CC);
        p1 = *reinterpret_cast<const float4*>(pc - CC + 4);
      }
      const float4 t0 = *reinterpret_cast<const float4*>(tm_x + kb);
      const float4 t1 = *reinterpret_cast<const float4*>(tm_x + kb + 4);
      const float cv[8] = {c0.x, c0.y, c0.z, c0.w, c1.x, c1.y, c1.z, c1.w};
      const float pv[8] = {p0.x, p0.y, p0.z, p0.w, p1.x, p1.y, p1.z, p1.w};
      const float tv[8] = {t0.x, t0.y, t0.z, t0.w, t1.x, t1.y, t1.z, t1.w};
      short8 h;
#pragma unroll
      for (int e = 0; e < 8; ++e)
        h[e] = (short)f2bf(fmaf(pv[e] - cv[e], tv[e], cv[e]));
      xa[m][kk] = h;
    }

  // ---- C-layout xc/xx (token=tok0+m*16+half*4+reg, ch=nt*16+col) ----
  float xcv[2][4][4], xxv[2][4][4];
#pragma unroll
  for (int m = 0; m < 2; ++m)
#pragma unroll
    for (int reg = 0; reg < 4; ++reg) {
      const int tok = tok0 + m * 16 + half * 4 + reg;
      const bool has = (tok & (TT - 1)) != 0;
#pragma unroll
      for (int nt = 0; nt < 4; ++nt) {
        const size_t o = (size_t)tok * CC + nt * 16 + col;
        const float cur = x[o];
        const float prv = has ? x[o - CC] : 0.f;
        xcv[m][nt][reg] = cur;
        xxv[m][nt][reg] = prv - cur;
      }
    }

  // ---- per-f pipeline: GEMM1 -> tanh -> LDS T -> GEMM2 -> stream ----
  auto process_f = [&](int f, const float* __restrict__ tmf,
                       float* __restrict__ gout) {
    f32x4 acc1[2][2];
#pragma unroll
    for (int m = 0; m < 2; ++m)
#pragma unroll
      for (int ntf = 0; ntf < 2; ++ntf) acc1[m][ntf] = (f32x4){0.f, 0.f, 0.f, 0.f};
    short8 b1[2][2];
#pragma unroll
    for (int ntf = 0; ntf < 2; ++ntf)
#pragma unroll
      for (int kk = 0; kk < 2; ++kk)
        b1[ntf][kk] = ldb8(w1T + (size_t)(f * 32 + ntf * 16 + col) * 64 + kk * 32 + half * 8);
#pragma unroll
    for (int m = 0; m < 2; ++m)
#pragma unroll
      for (int ntf = 0; ntf < 2; ++ntf)
#pragma unroll
        for (int kk = 0; kk < 2; ++kk)
          acc1[m][ntf] = __builtin_amdgcn_mfma_f32_16x16x32_bf16(
              xa[m][kk], b1[ntf][kk], acc1[m][ntf], 0, 0, 0);
    // tanh + transpose to aT
#pragma unroll
    for (int m = 0; m < 2; ++m)
#pragma unroll
      for (int ntf = 0; ntf < 2; ++ntf)
#pragma unroll
        for (int reg = 0; reg < 4; ++reg)
          aT[wid][m * 16 + half * 4 + reg][ntf * 16 + col] = tanh_f(acc1[m][ntf][reg]);
    short8 a2[2];
#pragma unroll
    for (int m = 0; m < 2; ++m)
      a2[m] = ldb8_lds(&aT[wid][m * 16 + col][half * 8]);
    f32x4 acc2[2][4];
#pragma unroll
    for (int m = 0; m < 2; ++m)
#pragma unroll
      for (int nt = 0; nt < 4; ++nt) acc2[m][nt] = (f32x4){0.f, 0.f, 0.f, 0.f};
    short8 b2[4];
#pragma unroll
    for (int nt = 0; nt < 4; ++nt)
      b2[nt] = ldb8(w2T + (size_t)f * 2048 + (nt * 16 + col) * 32 + half * 8);
#pragma unroll
    for (int m = 0; m < 2; ++m)
#pragma unroll
      for (int nt = 0; nt < 4; ++nt)
        acc2[m][nt] = __builtin_amdgcn_mfma_f32_16x16x32_bf16(
            a2[m], b2[nt], acc2[m][nt], 0, 0, 0);
    float tmf4[4];
#pragma unroll
    for (int nt = 0; nt < 4; ++nt) tmf4[nt] = tmf[nt * 16 + col];
#pragma unroll
    for (int m = 0; m < 2; ++m)
#pragma unroll
      for (int nt = 0; nt < 4; ++nt)
#pragma unroll
        for (int reg = 0; reg < 4; ++reg) {
          const float val = fmaf(xxv[m][nt][reg], tmf4[nt] + acc2[m][nt][reg],
                                 xcv[m][nt][reg]);
          if (gout)
            gout[(size_t)(tok0 + m * 16 + half * 4 + reg) * CC + nt * 16 + col] = val;
          else
            xT[wid][m * 16 + half * 4 + reg][nt * 16 + col] = val;
        }
  };

  process_f(1, tm_k, xk_o);
  process_f(2, tm_v, xv_o);
  process_f(3, tm_r, xr_o);
  process_f(4, tm_g, xg_o);
  process_f(0, tm_w, nullptr);   // xw -> LDS xT

  // ---- decay MLP: h = tanh(xw @ d1T^T'); wf = t_decay + h @ d2T ----
  short8 xwf[2][2];
#pragma unroll
  for (int m = 0; m < 2; ++m)
#pragma unroll
    for (int kk = 0; kk < 2; ++kk)
      xwf[m][kk] = ldb8_lds(&xT[wid][m * 16 + col][kk * 32 + half * 8]);
  f32x4 hcc[2][4];
#pragma unroll
  for (int m = 0; m < 2; ++m)
#pragma unroll
    for (int nt = 0; nt < 4; ++nt) hcc[m][nt] = (f32x4){0.f, 0.f, 0.f, 0.f};
  short8 bd[4][2];
#pragma unroll
  for (int nt = 0; nt < 4; ++nt)
#pragma unroll
    for (int kk = 0; kk < 2; ++kk)
      bd[nt][kk] = ldb8(d1T + (size_t)(nt * 16 + col) * 64 + kk * 32 + half * 8);
#pragma unroll
  for (int m = 0; m < 2; ++m)
#pragma unroll
    for (int nt = 0; nt < 4; ++nt)
#pragma unroll
      for (int kk = 0; kk < 2; ++kk)
        hcc[m][nt] = __builtin_amdgcn_mfma_f32_16x16x32_bf16(
            xwf[m][kk], bd[nt][kk], hcc[m][nt], 0, 0, 0);
  // tanh -> xT (xw dead)
#pragma unroll
  for (int m = 0; m < 2; ++m)
#pragma unroll
    for (int nt = 0; nt < 4; ++nt)
#pragma unroll
      for (int reg = 0; reg < 4; ++reg)
        xT[wid][m * 16 + half * 4 + reg][nt * 16 + col] = tanh_f(hcc[m][nt][reg]);
  short8 hf[2][2];
#pragma unroll
  for (int m = 0; m < 2; ++m)
#pragma unroll
    for (int kk = 0; kk < 2; ++kk)
      hf[m][kk] = ldb8_lds(&xT[wid][m * 16 + col][kk * 32 + half * 8]);
  f32x4 wfa[2][4];
#pragma unroll
  for (int m = 0; m < 2; ++m)
#pragma unroll
    for (int nt = 0; nt < 4; ++nt) wfa[m][nt] = (f32x4){0.f, 0.f, 0.f, 0.f};
#pragma unroll
  for (int nt = 0; nt < 4; ++nt)
#pragma unroll
    for (int kk = 0; kk < 2; ++kk)
      bd[nt][kk] = ldb8(d2T + (size_t)(nt * 16 + col) * 64 + kk * 32 + half * 8);
#pragma unroll
  for (int m = 0; m < 2; ++m)
#pragma unroll
    for (int nt = 0; nt < 4; ++nt)
#pragma unroll
      for (int kk = 0; kk < 2; ++kk)
        wfa[m][nt] = __builtin_amdgcn_mfma_f32_16x16x32_bf16(
            hf[m][kk], bd[nt][kk], wfa[m][nt], 0, 0, 0);
  float td4[4];
#pragma unroll
  for (int nt = 0; nt < 4; ++nt) td4[nt] = t_decay[nt * 16 + col];
#pragma unroll
  for (int m = 0; m < 2; ++m)
#pragma unroll
    for (int nt = 0; nt < 4; ++nt)
#pragma unroll
      for (int reg = 0; reg < 4; ++reg)
        rkdc[4 * ((size_t)(tok0 + m * 16 + half * 4 + reg) * CC + nt * 16 + col) + 2] =
            __expf(-__expf(wfa[m][nt][reg] + td4[nt]));
}

// ---- proj4 via MFMA (bf16 3-product split) — unchanged -------------------
__device__ __forceinline__ void load_afrag(
    const float* __restrict__ X, int tok0, int col, int half,
    short8 ah[2][2], short8 al[2][2])
{
#pragma unroll
  for (int m = 0; m < 2; ++m)
#pragma unroll
    for (int kk = 0; kk < 2; ++kk) {
      const float* p = X + (size_t)(tok0 + m * 16 + col) * CC + kk * 32 + half * 8;
      const float4 v0 = *reinterpret_cast<const float4*>(p);
      const float4 v1 = *reinterpret_cast<const float4*>(p + 4);
      const float vv[8] = {v0.x, v0.y, v0.z, v0.w, v1.x, v1.y, v1.z, v1.w};
      short8 h, l;
#pragma unroll
      for (int e = 0; e < 8; ++e) {
        const unsigned short hb = f2bf(vv[e]);
        h[e] = (short)hb;
        l[e] = (short)f2bf(vv[e] - bf2f(hb));
      }
      ah[m][kk] = h; al[m][kk] = l;
    }
}
__device__ __forceinline__ void load_bfrag(
    const float* __restrict__ W, int col, int half,
    short8 bh[4][2], short8 bl[4][2])
{
#pragma unroll
  for (int n = 0; n < 4; ++n)
#pragma unroll
    for (int kk = 0; kk < 2; ++kk) {
      const float* p = W + (size_t)(n * 16 + col) * CC + kk * 32 + half * 8;
      const float4 v0 = *reinterpret_cast<const float4*>(p);
      const float4 v1 = *reinterpret_cast<const float4*>(p + 4);
      const float vv[8] = {v0.x, v0.y, v0.z, v0.w, v1.x, v1.y, v1.z, v1.w};
      short8 h, l;
#pragma unroll
      for (int e = 0; e < 8; ++e) {
        const unsigned short hb = f2bf(vv[e]);
        h[e] = (short)hb;
        l[e] = (short)f2bf(vv[e] - bf2f(hb));
      }
      bh[n][kk] = h; bl[n][kk] = l;
    }
}
__device__ __forceinline__ void gemm_acc(
    const short8 ah[2][2], const short8 al[2][2],
    const short8 bh[4][2], const short8 bl[4][2], f32x4 acc[2][4])
{
#pragma unroll
  for (int m = 0; m < 2; ++m)
#pragma unroll
    for (int n = 0; n < 4; ++n) {
      f32x4 a = acc[m][n];
#pragma unroll
      for (int kk = 0; kk < 2; ++kk) {
        a = __builtin_amdgcn_mfma_f32_16x16x32_bf16(ah[m][kk], bh[n][kk], a, 0, 0, 0);
        a = __builtin_amdgcn_mfma_f32_16x16x32_bf16(ah[m][kk], bl[n][kk], a, 0, 0, 0);
        a = __builtin_amdgcn_mfma_f32_16x16x32_bf16(al[m][kk], bh[n][kk], a, 0, 0, 0);
      }
      acc[m][n] = a;
    }
}

__global__ __launch_bounds__(256) void proj4_mfma_kernel(
    const float* __restrict__ xk_i, const float* __restrict__ xv_i,
    const float* __restrict__ xr_i, const float* __restrict__ xg_i,
    const float* __restrict__ u,
    const float* __restrict__ Wr, const float* __restrict__ Wk, const float* __restrict__ Wv,
    const float* __restrict__ Wg,
    float* __restrict__ rkdc, float* __restrict__ v_o, float* __restrict__ g_o)
{
  const int lane = threadIdx.x & 63;
  const int wid = threadIdx.x >> 6;
  const int col = lane & 15, half = lane >> 4;
  const int tok0 = blockIdx.x * 128 + wid * 32;

  short8 ah[2][2], al[2][2], bh[4][2], bl[4][2];
  f32x4 accr[2][4], acck[2][4];

  load_bfrag(Wr, col, half, bh, bl);
  load_afrag(xr_i, tok0, col, half, ah, al);
#pragma unroll
  for (int m = 0; m < 2; ++m)
#pragma unroll
    for (int n = 0; n < 4; ++n) accr[m][n] = (f32x4){0.f, 0.f, 0.f, 0.f};
  gemm_acc(ah, al, bh, bl, accr);

  load_bfrag(Wk, col, half, bh, bl);
  load_afrag(xk_i, tok0, col, half, ah, al);
#pragma unroll
  for (int m = 0; m < 2; ++m)
#pragma unroll
    for (int n = 0; n < 4; ++n) acck[m][n] = (f32x4){0.f, 0.f, 0.f, 0.f};
  gemm_acc(ah, al, bh, bl, acck);

  float uv[4];
#pragma unroll
  for (int n = 0; n < 4; ++n) uv[n] = u[n * 16 + col];
  float ctv[2][4];
#pragma unroll
  for (int m = 0; m < 2; ++m)
#pragma unroll
    for (int reg = 0; reg < 4; ++reg) {
      float p = 0.f;
#pragma unroll
      for (int n = 0; n < 4; ++n)
        p += accr[m][n][reg] * uv[n] * acck[m][n][reg];
      p += __shfl_xor(p, 1, 64);
      p += __shfl_xor(p, 2, 64);
      p += __shfl_xor(p, 4, 64);
      p += __shfl_xor(p, 8, 64);
      ctv[m][reg] = p;
    }

#pragma unroll
  for (int m = 0; m < 2; ++m)
#pragma unroll
    for (int n = 0; n < 4; ++n)
#pragma unroll
      for (int reg = 0; reg < 4; ++reg) {
        const int token = tok0 + m * 16 + half * 4 + reg;
        const size_t o = (size_t)token * CC + n * 16 + col;
        rkdc[4 * o + 0] = accr[m][n][reg];
        rkdc[4 * o + 1] = acck[m][n][reg];
        rkdc[4 * o + 3] = ctv[m][reg];
      }

  load_bfrag(Wv, col, half, bh, bl);
  load_afrag(xv_i, tok0, col, half, ah, al);
#pragma unroll
  for (int m = 0; m < 2; ++m)
#pragma unroll
    for (int n = 0; n < 4; ++n) accr[m][n] = (f32x4){0.f, 0.f, 0.f, 0.f};
  gemm_acc(ah, al, bh, bl, accr);
#pragma unroll
  for (int m = 0; m < 2; ++m)
#pragma unroll
    for (int n = 0; n < 4; ++n)
#pragma unroll
      for (int reg = 0; reg < 4; ++reg) {
        const int token = tok0 + m * 16 + half * 4 + reg;
        v_o[(size_t)token * CC + n * 16 + col] = accr[m][n][reg];
      }

  load_bfrag(Wg, col, half, bh, bl);
  load_afrag(xg_i, tok0, col, half, ah, al);
#pragma unroll
  for (int m = 0; m < 2; ++m)
#pragma unroll
    for (int n = 0; n < 4; ++n) accr[m][n] = (f32x4){0.f, 0.f, 0.f, 0.f};
  gemm_acc(ah, al, bh, bl, accr);
#pragma unroll
  for (int m = 0; m < 2; ++m)
#pragma unroll
    for (int n = 0; n < 4; ++n)
#pragma unroll
      for (int reg = 0; reg < 4; ++reg) {
        const int token = tok0 + m * 16 + half * 4 + reg;
        const float gg = accr[m][n][reg];
        g_o[(size_t)token * CC + n * 16 + col] = gg / (1.f + __expf(-gg));
      }
}

// ---- A: chunk-local state ------------------------------------------------
__global__ __launch_bounds__(256) void chunkA_kernel(
    const float4* __restrict__ rkdc, const float* __restrict__ v_i,
    float* __restrict__ Sloc, float* __restrict__ Dp)
{
  const int lane = threadIdx.x & 63;
  const int bch = __builtin_amdgcn_readfirstlane((blockIdx.x << 2) + (threadIdx.x >> 6));
  const float4* fq = rkdc + (size_t)bch * (CL * CC);
  const float* dq = (const float*)fq + 4 * lane + 2;
  const float* vq = v_i + (size_t)bch * (CL * CC) + lane;

  float S[CC];
#pragma unroll
  for (int i = 0; i < CC; ++i) S[i] = 0.f;
  float dp = 1.f;

  for (int t = 0; t < CL; ++t) {
    const float4* ft = fq + t * CC;
    const float vv = vq[t * CC];
    dp *= dq[4 * t * CC];
#pragma unroll
    for (int i = 0; i < CC; ++i) {
      const float4 f = ft[i];
      S[i] = fmaf(f.z, S[i], f.y * vv);
    }
  }
  float* so = Sloc + (size_t)bch * (CC * CC) + lane;
#pragma unroll
  for (int i = 0; i < CC; ++i) so[i * CC] = S[i];
  Dp[(size_t)bch * CC + lane] = dp;
}

// ---- B: in-place combine -------------------------------------------------
__global__ __launch_bounds__(1024) void combine_kernel(
    float* __restrict__ buf, const float* __restrict__ Dp)
{
  const int b = blockIdx.x, tid = threadIdx.x;
  __shared__ float sDp[NCH * CC];
  for (int idx = tid; idx < NCH * CC; idx += 1024)
    sDp[idx] = Dp[(size_t)b * NCH * CC + idx];
  __syncthreads();
  float run[4] = {0.f, 0.f, 0.f, 0.f};
  for (int ch = 0; ch < NCH; ++ch) {
    const size_t base = ((size_t)(b * NCH + ch)) * (CC * CC);
    const float* drow = sDp + ch * CC;
#pragma unroll
    for (int k2 = 0; k2 < 4; ++k2) {
      const int idx = tid + (k2 << 10);
      const float tmp = buf[base + idx];
      buf[base + idx] = run[k2];
      run[k2] = fmaf(run[k2], drow[idx >> 6], tmp);
    }
  }
}

// ---- C: emit + GroupNorm + *g + @Wo.T fused ------------------------------
__global__ __launch_bounds__(256) void scanC_kernel(
    const float4* __restrict__ rkdc, const float* __restrict__ v_i,
    const float* __restrict__ S0, const float* __restrict__ g_i,
    const float* __restrict__ ln_w, const float* __restrict__ ln_b,
    const float* __restrict__ Wo, float* __restrict__ out)
{
  __shared__ float WoT[4096];
  for (int idx = threadIdx.x; idx < 4096; idx += 256) {
    const int c = idx >> 6, jj = idx & 63;
    WoT[idx] = Wo[jj * 64 + c];
  }
  __syncthreads();

  const int lane = threadIdx.x & 63;
  const int bch = __builtin_amdgcn_readfirstlane((blockIdx.x << 2) + (threadIdx.x >> 6));
  const float4* fq = rkdc + (size_t)bch * (CL * CC);
  const float* vq = v_i + (size_t)bch * (CL * CC) + lane;
  const float* gq = g_i + (size_t)bch * (CL * CC) + lane;
  float* oq = out + (size_t)bch * (CL * CC) + lane;
  const float lnw = ln_w[lane], lnb = ln_b[lane];

  float S[CC];
  const float* si = S0 + (size_t)bch * (CC * CC) + lane;
#pragma unroll
  for (int i = 0; i < CC; ++i) S[i] = si[i * CC];

  for (int t = 0; t < CL; ++t) {
    const float4* ft = fq + t * CC;
    const float vv = vq[t * CC];
    float y0, y1;
    {
      const float4 f = ft[0];
      y0 = fmaf(f.x, S[0], f.w * vv);
      S[0] = fmaf(f.z, S[0], f.y * vv);
    }
    {
      const float4 f = ft[1];
      y1 = f.x * S[1];
      S[1] = fmaf(f.z, S[1], f.y * vv);
    }
#pragma unroll
    for (int i = 2; i < CC; i += 2) {
      const float4 fa = ft[i];
      y0 = fmaf(fa.x, S[i], y0);
      S[i] = fmaf(fa.z, S[i], fa.y * vv);
      const float4 fb = ft[i + 1];
      y1 = fmaf(fb.x, S[i + 1], y1);
      S[i + 1] = fmaf(fb.z, S[i + 1], fb.y * vv);
    }
    const float y = y0 + y1;

    const float s1 = wave_red_sum(y);
    const float s2 = wave_red_sum(y * y);
    const float mu = s1 * (1.f / CC);
    const float var = s2 * (1.f / CC) - mu * mu;
    const float z = (y - mu) * rsqrtf(var + GN_EPS) * lnw + lnb;
    const float sz = z * gq[t * CC];
    float acc = 0.f;
#pragma unroll
    for (int c = 0; c < CC; ++c) acc = fmaf(rl(sz, c), WoT[c * 64 + lane], acc);
    oq[t * CC] = acc;
  }
}

extern "C" void kernel_launch(void* const* d_in, const int* in_sizes, int n_in,
                              void* d_out, int out_size, void* d_ws, size_t ws_size,
                              hipStream_t stream) {
  const float* x       = (const float*)d_in[0];
  const float* tm_x    = (const float*)d_in[1];
  const float* tm_w    = (const float*)d_in[2];
  const float* tm_k    = (const float*)d_in[3];
  const float* tm_v    = (const float*)d_in[4];
  const float* tm_r    = (const float*)d_in[5];
  const float* tm_g    = (const float*)d_in[6];
  const float* maa_w1  = (const float*)d_in[7];
  const float* maa_w2  = (const float*)d_in[8];
  const float* t_decay = (const float*)d_in[9];
  const float* dec_w1  = (const float*)d_in[10];
  const float* dec_w2  = (const float*)d_in[11];
  const float* u       = (const float*)d_in[12];
  const float* Wr      = (const float*)d_in[13];
  const float* Wk      = (const float*)d_in[14];
  const float* Wv      = (const float*)d_in[15];
  const float* Wg      = (const float*)d_in[16];
  const float* Wo      = (const float*)d_in[17];
  const float* ln_w    = (const float*)d_in[18];
  const float* ln_b    = (const float*)d_in[19];

  const size_t M = (size_t)BT * CC;  // 4.19M floats
  float* ws   = (float*)d_ws;
  float* xk_o = ws;                  // [0,M)   dead after proj4
  float* xv_o = ws + M;              // [M,2M)  dead after proj4
  float* xr_o = ws + 2 * M;          // [2M,3M) dead after proj4
  float* xg_o = ws + 3 * M;          // [3M,4M) dead after proj4
  float* g_o  = ws + 4 * M;          // alive until scanC
  float* v_o  = ws + 5 * M;          // alive until scanC
  float* rkdc = ws + 6 * M;          // [6M,10M) float4 stream
  float* scb  = ws;                  // Sloc==S0 (in-place), 2M floats
  float* Dp   = ws + 2 * M;          // aliases dead xr_o
  float* w1T  = ws + 10 * M;         // 10240
  float* w2T  = w1T + 160 * 64;      // 10240
  float* d1T  = w2T + 5 * 64 * 32;   // 4096
  float* d2T  = d1T + 4096;          // 4096
  float* out  = (float*)d_out;

  preT_kernel<<<64, 256, 0, stream>>>(
      maa_w1, maa_w2, dec_w1, dec_w2, w1T, w2T, d1T, d2T);

  mix_mfma_kernel<<<BT / 128, 256, 0, stream>>>(
      x, tm_x, tm_w, tm_k, tm_v, tm_r, tm_g,
      w1T, w2T, d1T, d2T, t_decay,
      xk_o, xv_o, xr_o, xg_o, rkdc);

  proj4_mfma_kernel<<<BT / 128, 256, 0, stream>>>(
      xk_o, xv_o, xr_o, xg_o, u, Wr, Wk, Wv, Wg, rkdc, v_o, g_o);

  chunkA_kernel<<<(BB * NCH) / 4, 256, 0, stream>>>(
      (const float4*)rkdc, v_o, scb, Dp);

  combine_kernel<<<BB, 1024, 0, stream>>>(scb, Dp);

  scanC_kernel<<<(BB * NCH) / 4, 256, 0, stream>>>(
      (const float4*)rkdc, v_o, scb, g_o, ln_w, ln_b, Wo, out);
}